// Round 15
// baseline (363.176 us; speedup 1.0000x reference)
//
#include <hip/hip_runtime.h>

// DyHuCoG: out = (E + A*E + A*(A*E)) / 3
// E: [N,32] f32, A: COO (vals f32, row i32, col i32), N=100001, nE=6400000.
//
// Pipeline (atomic-free partition, 4B edges, int8 gathers + int32 accum):
//   0) zero scale scalars; absmax(emb)
//   1) tile_hist: per-4096-edge tile bucket histogram (256-row buckets)
//   2) colscan:   in-place exclusive scan down each bucket column
//   3) scan_buckets: bucket bases
//   4) partition_edges2: LDS counting-sort per tile (NO global atomics),
//      coalesced run writes of ONE uint2 array {col|rowlow<<17, q15 val}
//   5) csr_sort4: per bucket-half LDS-staged counting sort -> exact CSR
//      (cv2[u32] = col | q15<<17, rowptr)
//   6) quant emb -> xq int8 (global scale = absmax/127); gather set 3.2MB
//      fits per-XCD L2
//   7) spmm_l1_q8: int32 accumulate (q15 x int8, exact), y1h = bf16(y1),
//      block-reduced atomicMax(|y1|)
//   8) quant y1h -> y1q int8
//   9) spmm_combine_q8: out = (E + y1 + A*y1)/3

constexpr int D = 32;
constexpr int RPB_LOG = 8;               // rows per bucket = 256
constexpr int RPB = 1 << RPB_LOG;
constexpr int MAXNB = 512;               // supports n <= 131072 (17-bit col)
constexpr int TILE = 4096;               // edges per partition tile
constexpr int PT2 = 512;                 // partition threads
constexpr int CAP = 9728;                // LDS staging capacity (edges/half)
constexpr float QSCALE = 32768.0f;       // 15-bit val quantization
constexpr float QINV = 1.0f / 32768.0f;

__device__ __forceinline__ unsigned short f2bf(float f) {
    unsigned u = __float_as_uint(f);
    unsigned r = (u + 0x7FFFu + ((u >> 16) & 1u)) >> 16;   // RNE
    return (unsigned short)r;
}
__device__ __forceinline__ float bf2f(unsigned short h) {
    return __uint_as_float((unsigned)h << 16);
}

__global__ void zero_f32(float* __restrict__ p, int n) {
    int i = blockIdx.x * blockDim.x + threadIdx.x;
    if (i < n) p[i] = 0.0f;
}
__global__ void zero2_u32(unsigned* __restrict__ p) {
    p[0] = 0u;
    p[1] = 0u;
}

// global absmax of f32 array -> bits (positive-float bit order == value order)
__global__ __launch_bounds__(256) void absmax_f32(
    const float* __restrict__ in, unsigned* __restrict__ outBits, int n) {
    __shared__ float s[4];
    float m = 0.0f;
    for (int i = blockIdx.x * 256 + threadIdx.x; i < n; i += gridDim.x * 256)
        m = fmaxf(m, fabsf(in[i]));
    for (int o = 32; o > 0; o >>= 1) m = fmaxf(m, __shfl_down(m, o, 64));
    int wid = threadIdx.x >> 6;
    if ((threadIdx.x & 63) == 0) s[wid] = m;
    __syncthreads();
    if (threadIdx.x == 0) {
        float mm = fmaxf(fmaxf(s[0], s[1]), fmaxf(s[2], s[3]));
        atomicMax(outBits, __float_as_uint(mm));
    }
}

// quantize f32 -> int8 with global scale max/127
__global__ void quant8_f32(const float* __restrict__ in,
                           const unsigned* __restrict__ maxBits,
                           signed char* __restrict__ out, int n) {
    int i = blockIdx.x * blockDim.x + threadIdx.x;
    if (i >= n) return;
    float mx = fmaxf(__uint_as_float(*maxBits), 1e-20f);
    float inv = 127.0f / mx;
    int q = __float2int_rn(in[i] * inv);
    out[i] = (signed char)max(-127, min(127, q));
}
// quantize bf16 -> int8 with global scale
__global__ void quant8_bf16(const unsigned short* __restrict__ in,
                            const unsigned* __restrict__ maxBits,
                            signed char* __restrict__ out, int n) {
    int i = blockIdx.x * blockDim.x + threadIdx.x;
    if (i >= n) return;
    float mx = fmaxf(__uint_as_float(*maxBits), 1e-20f);
    float inv = 127.0f / mx;
    int q = __float2int_rn(bf2f(in[i]) * inv);
    out[i] = (signed char)max(-127, min(127, q));
}

// ------- 1) per-tile bucket histogram -> tileCnt[tile][NB] (coalesced) ----
__global__ __launch_bounds__(256) void tile_hist(
    const int* __restrict__ row, int* __restrict__ tileCnt, int nE, int NB) {
    __shared__ int h[MAXNB];
    int tile = blockIdx.x;
    int base = tile * TILE;
    int n = min(TILE, nE - base);
    int t = threadIdx.x;
    for (int i = t; i < NB; i += 256) h[i] = 0;
    __syncthreads();
    for (int i = t; i < n; i += 256)
        atomicAdd(&h[row[base + i] >> RPB_LOG], 1);
    __syncthreads();
    for (int i = t; i < NB; i += 256)
        tileCnt[(size_t)tile * NB + i] = h[i];
}

// ------- 2) in-place exclusive column scan + bucket totals ---------------
__global__ __launch_bounds__(256) void colscan(
    int* __restrict__ tileCnt, int* __restrict__ cnt, int nTiles, int NB) {
    __shared__ int s2[256];
    __shared__ int carryS;
    int b = blockIdx.x, t = threadIdx.x;
    if (t == 0) carryS = 0;
    __syncthreads();
    for (int c0 = 0; c0 < nTiles; c0 += 1024) {
        int v[4], idx[4];
        int sum = 0;
#pragma unroll
        for (int k = 0; k < 4; ++k) {
            idx[k] = c0 + t * 4 + k;
            v[k] = (idx[k] < nTiles) ? tileCnt[(size_t)idx[k] * NB + b] : 0;
            sum += v[k];
        }
        s2[t] = sum;
        __syncthreads();
        for (int o = 1; o < 256; o <<= 1) {
            int x = (t >= o) ? s2[t - o] : 0;
            __syncthreads();
            s2[t] += x;
            __syncthreads();
        }
        int run = ((t == 0) ? 0 : s2[t - 1]) + carryS;
#pragma unroll
        for (int k = 0; k < 4; ++k) {
            if (idx[k] < nTiles) tileCnt[(size_t)idx[k] * NB + b] = run;
            run += v[k];
        }
        __syncthreads();
        if (t == 0) carryS += s2[255];
        __syncthreads();
    }
    if (t == 0) cnt[b] = carryS;
}

// ---------------- 3) exclusive scan of bucket counts (NB <= 512) ---------
__global__ __launch_bounds__(512) void scan_buckets(
    const int* __restrict__ cnt, int* __restrict__ bases, int NB, int nE) {
    __shared__ int s[MAXNB];
    int t = threadIdx.x;
    s[t] = (t < NB) ? cnt[t] : 0;
    __syncthreads();
    for (int o = 1; o < 512; o <<= 1) {
        int v = (t >= o) ? s[t - o] : 0;
        __syncthreads();
        s[t] += v;
        __syncthreads();
    }
    if (t < NB) bases[t] = (t == 0) ? 0 : s[t - 1];
    if (t == 0) bases[NB] = nE;
}

// ------- 4) tiled partition, NO global atomics, coalesced writes ---------
__global__ __launch_bounds__(PT2) void partition_edges2(
    const int* __restrict__ row, const int* __restrict__ col,
    const float* __restrict__ vals, const int* __restrict__ bases,
    const int* __restrict__ tileCnt, uint2* __restrict__ cv, int nE, int NB) {
    __shared__ uint2 buf[TILE];            // 32 KB
    __shared__ unsigned short bkt[TILE];   // 8 KB
    __shared__ int hist[MAXNB];            // 2 KB (-> runbase - runoff0)
    __shared__ int runoff[MAXNB];          // 2 KB (local excl scan -> cursor)
    __shared__ int s2[PT2];                // 2 KB
    int t = threadIdx.x;
    int tile = blockIdx.x;
    int base = tile * TILE;
    int n = min(TILE, nE - base);
    if (n <= 0) return;
    for (int i = t; i < NB; i += PT2) hist[i] = 0;
    __syncthreads();
    for (int i = t; i < n; i += PT2)
        atomicAdd(&hist[row[base + i] >> RPB_LOG], 1);
    __syncthreads();
    // local exclusive scan of hist -> runoff (1 elem/thread covers 512)
    {
        int a0 = (t < NB) ? hist[t] : 0;
        s2[t] = a0;
        __syncthreads();
        for (int o = 1; o < PT2; o <<= 1) {
            int v = (t >= o) ? s2[t - o] : 0;
            __syncthreads();
            s2[t] += v;
            __syncthreads();
        }
        if (t < NB) runoff[t] = s2[t] - a0;   // exclusive
    }
    __syncthreads();
    // hist[b] := global run base - runoff0[b]
    for (int i = t; i < NB; i += PT2)
        hist[i] = bases[i] + tileCnt[(size_t)tile * NB + i] - runoff[i];
    __syncthreads();
    // reorder into LDS bucket-major
    for (int i = t; i < n; i += PT2) {
        int r = row[base + i];
        int b = r >> RPB_LOG;
        int slot = atomicAdd(&runoff[b], 1);
        float v = vals[base + i];
        int q = __float2int_rn(v * QSCALE);
        q = max(0, min(32767, q));
        uint2 p;
        p.x = (unsigned)col[base + i] | ((unsigned)(r & (RPB - 1)) << 17);
        p.y = (unsigned)q;
        buf[slot] = p;
        bkt[slot] = (unsigned short)b;
    }
    __syncthreads();
    // coalesced run writes: dest = hist[b] + slot (slot == i)
    for (int i = t; i < n; i += PT2)
        cv[hist[bkt[i]] + i] = buf[i];
}

// ------- 5) per bucket-half LDS-staged counting sort -> exact CSR --------
__global__ __launch_bounds__(512) void csr_sort4(
    const int* __restrict__ bases, const uint2* __restrict__ cv,
    unsigned* __restrict__ cv2, int* __restrict__ rowptr, int n, int nE) {
    __shared__ unsigned stage[CAP];        // 38 KB
    __shared__ int hist_s[RPB];            // 1 KB
    __shared__ int cur_s[RPB];             // 1 KB
    int t = threadIdx.x;
    int b = blockIdx.x >> 1;
    int h = blockIdx.x & 1;
    int s = bases[b], e = bases[b + 1];
    if (t < RPB) hist_s[t] = 0;
    __syncthreads();
    for (int i = s + t; i < e; i += 512)
        atomicAdd(&hist_s[cv[i].x >> 17], 1);
    __syncthreads();
    if (t < RPB) cur_s[t] = hist_s[t];
    __syncthreads();
    for (int o = 1; o < RPB; o <<= 1) {       // inclusive scan
        int v = 0;
        if (t < RPB && t >= o) v = cur_s[t - o];
        __syncthreads();
        if (t < RPB) cur_s[t] += v;
        __syncthreads();
    }
    int excl = 0;
    if (t < RPB) excl = (t == 0) ? 0 : cur_s[t - 1];
    int half_lo = h << 7;                     // h*128
    __syncthreads();
    int base_h = (half_lo == 0) ? 0 : cur_s[half_lo - 1];
    int end_h  = cur_s[half_lo + 127];
    int cnt_h  = end_h - base_h;
    __syncthreads();
    if (t < RPB) {
        if ((t >> 7) == h) {
            int r = (b << RPB_LOG) + t;
            if (r < n) rowptr[r] = s + excl;
            cur_s[t] = excl - base_h;         // local staging cursor
        }
    }
    if (b == 0 && h == 0 && t == 0) rowptr[n] = nE;
    __syncthreads();
    bool fits = (cnt_h <= CAP);
    for (int i = s + t; i < e; i += 512) {
        uint2 p = cv[i];
        int r = (int)(p.x >> 17);
        if ((r >> 7) != h) continue;
        int slot = atomicAdd(&cur_s[r], 1);
        unsigned packed = (p.x & 0x1FFFFu) | (p.y << 17);
        if (fits) stage[slot] = packed;
        else      cv2[s + base_h + slot] = packed;
    }
    __syncthreads();
    if (fits) {
        int dst = s + base_h;
        for (int j = t; j < cnt_h; j += 512)
            cv2[dst + j] = stage[j];
    }
}

// ------- 7) layer-1 SpMM: int32 accumulate, y1h bf16 + block max ---------
__global__ __launch_bounds__(256) void spmm_l1_q8(
    const int* __restrict__ ptr, const unsigned* __restrict__ cv,
    const signed char* __restrict__ xq, const unsigned* __restrict__ xMaxBits,
    unsigned short* __restrict__ yh, unsigned* __restrict__ yMaxBits,
    int nRows) {
    __shared__ float smax[4];
    int g = (blockIdx.x * 256 + threadIdx.x) >> 5;
    int lane = threadIdx.x & 31;
    float av = 0.0f;
    if (g < nRows) {
        int e = ptr[g], end = ptr[g + 1];
        int acc = 0;
        for (; e + 8 <= end; e += 8) {
            unsigned q0 = cv[e], q1 = cv[e + 1], q2 = cv[e + 2], q3 = cv[e + 3];
            unsigned q4 = cv[e + 4], q5 = cv[e + 5], q6 = cv[e + 6], q7 = cv[e + 7];
            int x0 = xq[(size_t)(q0 & 0x1FFFFu) * D + lane];
            int x1 = xq[(size_t)(q1 & 0x1FFFFu) * D + lane];
            int x2 = xq[(size_t)(q2 & 0x1FFFFu) * D + lane];
            int x3 = xq[(size_t)(q3 & 0x1FFFFu) * D + lane];
            int x4 = xq[(size_t)(q4 & 0x1FFFFu) * D + lane];
            int x5 = xq[(size_t)(q5 & 0x1FFFFu) * D + lane];
            int x6 = xq[(size_t)(q6 & 0x1FFFFu) * D + lane];
            int x7 = xq[(size_t)(q7 & 0x1FFFFu) * D + lane];
            acc += (int)(q0 >> 17) * x0;
            acc += (int)(q1 >> 17) * x1;
            acc += (int)(q2 >> 17) * x2;
            acc += (int)(q3 >> 17) * x3;
            acc += (int)(q4 >> 17) * x4;
            acc += (int)(q5 >> 17) * x5;
            acc += (int)(q6 >> 17) * x6;
            acc += (int)(q7 >> 17) * x7;
        }
        for (; e < end; ++e) {
            unsigned q = cv[e];
            acc += (int)(q >> 17) * (int)xq[(size_t)(q & 0x1FFFFu) * D + lane];
        }
        float xs = fmaxf(__uint_as_float(*xMaxBits), 1e-20f) * (1.0f / 127.0f);
        float y = (float)acc * (QINV * xs);
        yh[(size_t)g * D + lane] = f2bf(y);
        av = fabsf(y);
    }
    for (int o = 32; o > 0; o >>= 1) av = fmaxf(av, __shfl_down(av, o, 64));
    int wid = threadIdx.x >> 6;
    if ((threadIdx.x & 63) == 0) smax[wid] = av;
    __syncthreads();
    if (threadIdx.x == 0) {
        float mm = fmaxf(fmaxf(smax[0], smax[1]), fmaxf(smax[2], smax[3]));
        atomicMax(yMaxBits, __float_as_uint(mm));
    }
}

// ------- 9) layer-2 SpMM fused combine: out = (E + y1 + A*y1)/3 ----------
__global__ __launch_bounds__(256) void spmm_combine_q8(
    const int* __restrict__ ptr, const unsigned* __restrict__ cv,
    const signed char* __restrict__ y1q, const unsigned* __restrict__ yMaxBits,
    const unsigned short* __restrict__ y1h, const float* __restrict__ emb,
    float* __restrict__ out, int nRows) {
    int g = (blockIdx.x * 256 + threadIdx.x) >> 5;
    if (g >= nRows) return;
    int lane = threadIdx.x & 31;
    int e = ptr[g], end = ptr[g + 1];
    int acc = 0;
    for (; e + 8 <= end; e += 8) {
        unsigned q0 = cv[e], q1 = cv[e + 1], q2 = cv[e + 2], q3 = cv[e + 3];
        unsigned q4 = cv[e + 4], q5 = cv[e + 5], q6 = cv[e + 6], q7 = cv[e + 7];
        int x0 = y1q[(size_t)(q0 & 0x1FFFFu) * D + lane];
        int x1 = y1q[(size_t)(q1 & 0x1FFFFu) * D + lane];
        int x2 = y1q[(size_t)(q2 & 0x1FFFFu) * D + lane];
        int x3 = y1q[(size_t)(q3 & 0x1FFFFu) * D + lane];
        int x4 = y1q[(size_t)(q4 & 0x1FFFFu) * D + lane];
        int x5 = y1q[(size_t)(q5 & 0x1FFFFu) * D + lane];
        int x6 = y1q[(size_t)(q6 & 0x1FFFFu) * D + lane];
        int x7 = y1q[(size_t)(q7 & 0x1FFFFu) * D + lane];
        acc += (int)(q0 >> 17) * x0;
        acc += (int)(q1 >> 17) * x1;
        acc += (int)(q2 >> 17) * x2;
        acc += (int)(q3 >> 17) * x3;
        acc += (int)(q4 >> 17) * x4;
        acc += (int)(q5 >> 17) * x5;
        acc += (int)(q6 >> 17) * x6;
        acc += (int)(q7 >> 17) * x7;
    }
    for (; e < end; ++e) {
        unsigned q = cv[e];
        acc += (int)(q >> 17) * (int)y1q[(size_t)(q & 0x1FFFFu) * D + lane];
    }
    float ys = fmaxf(__uint_as_float(*yMaxBits), 1e-20f) * (1.0f / 127.0f);
    size_t idx = (size_t)g * D + lane;
    out[idx] = (emb[idx] + bf2f(y1h[idx]) + (float)acc * (QINV * ys))
               * (1.0f / 3.0f);
}

// =================== atomic fallback ===================
__global__ __launch_bounds__(256) void spmm_atomic(
    const int* __restrict__ row, const int* __restrict__ col,
    const float* __restrict__ vals, const float* __restrict__ x,
    float* __restrict__ y, int nEdges, float scale) {
    long long t = (long long)blockIdx.x * blockDim.x + threadIdx.x;
    int e = (int)(t >> 5);
    if (e >= nEdges) return;
    int d = (int)(t & 31);
    float g = vals[e] * scale * x[(long long)col[e] * D + d];
    atomicAdd(&y[(long long)row[e] * D + d], g);
}
__global__ void combine_third(const float* __restrict__ emb,
                              const float* __restrict__ y1,
                              float* __restrict__ out, int n) {
    int i = blockIdx.x * blockDim.x + threadIdx.x;
    if (i < n) out[i] = (emb[i] + y1[i]) * (1.0f / 3.0f);
}

extern "C" void kernel_launch(void* const* d_in, const int* in_sizes, int n_in,
                              void* d_out, int out_size, void* d_ws, size_t ws_size,
                              hipStream_t stream) {
    const float* emb  = (const float*)d_in[0];
    const float* vals = (const float*)d_in[1];
    const int*   row  = (const int*)d_in[2];
    const int*   col  = (const int*)d_in[3];
    float* out = (float*)d_out;

    const int nElem  = in_sizes[0];          // N * 32
    const int nEdges = in_sizes[1];
    const int n      = nElem / D;            // 100001
    const int NB     = (n + RPB - 1) >> RPB_LOG;   // 391
    const int BLK = 256;
    const int nTiles = (nEdges + TILE - 1) / TILE; // 1563

    // workspace layout:
    //   misc(cnt,bases,rowptr,scalars) | cv(uint2 8B*nE) | cv2(u32 4B*nE)
    //   tileCnt aliases cv2 (dead before csr_sort4 writes cv2)
    //   y1h(2B)/xq(1B)/y1q(1B) alias cv (dead after csr_sort4)
    size_t off_cnt    = 0;                                    // NB ints
    size_t off_bases  = off_cnt + (size_t)NB * 4;             // NB+1 ints
    size_t off_rowptr = off_bases + (size_t)(NB + 1) * 4;     // n+1 ints
    size_t off_scal   = off_rowptr + (size_t)(n + 1) * 4;     // 2 u32
    size_t off_cv     = (off_scal + 8 + 63) & ~(size_t)63;
    size_t off_cv2    = off_cv + (size_t)nEdges * 8;
    size_t need       = off_cv2 + (size_t)nEdges * 4;

    bool aliasFit   = ((size_t)nElem * 4 <= (size_t)nEdges * 8);
    bool tileCntFit = ((size_t)nTiles * NB * 4 <= (size_t)nEdges * 4);
    bool ok = (NB <= MAXNB) && (n <= 131072) && (ws_size >= need) &&
              aliasFit && tileCntFit;

    if (!ok) {
        // fallback: atomic-scatter path (needs nElem floats)
        if (ws_size < (size_t)nElem * 4) return;
        float* y1 = (float*)d_ws;
        zero_f32<<<(nElem + BLK - 1) / BLK, BLK, 0, stream>>>(y1, nElem);
        long long threads = (long long)nEdges * 32;
        int blocks = (int)((threads + BLK - 1) / BLK);
        spmm_atomic<<<blocks, BLK, 0, stream>>>(row, col, vals, emb, y1, nEdges, 1.0f);
        combine_third<<<(nElem + BLK - 1) / BLK, BLK, 0, stream>>>(emb, y1, out, nElem);
        spmm_atomic<<<blocks, BLK, 0, stream>>>(row, col, vals, y1, out, nEdges, 1.0f / 3.0f);
        return;
    }

    char* ws = (char*)d_ws;
    int*            cnt     = (int*)(ws + off_cnt);
    int*            bases   = (int*)(ws + off_bases);
    int*            rowptr  = (int*)(ws + off_rowptr);
    unsigned*       scal    = (unsigned*)(ws + off_scal);     // [embMax, y1Max]
    uint2*          cv      = (uint2*)(ws + off_cv);
    unsigned*       cv2     = (unsigned*)(ws + off_cv2);
    int*            tileCnt = (int*)(ws + off_cv2);           // alias
    unsigned short* y1h     = (unsigned short*)(ws + off_cv); // alias (cv dead)
    signed char*    xq      = (signed char*)(ws + off_cv + (size_t)nElem * 2);
    signed char*    y1q     = (signed char*)(ws + off_cv + (size_t)nElem * 3);

    // 0) zero scale scalars; absmax(emb)
    zero2_u32<<<1, 1, 0, stream>>>(scal);
    absmax_f32<<<1024, 256, 0, stream>>>(emb, &scal[0], nElem);

    // 1) per-tile histograms
    tile_hist<<<nTiles, 256, 0, stream>>>(row, tileCnt, nEdges, NB);

    // 2) column scan (in-place) + bucket totals
    colscan<<<NB, 256, 0, stream>>>(tileCnt, cnt, nTiles, NB);

    // 3) bucket bases
    scan_buckets<<<1, 512, 0, stream>>>(cnt, bases, NB, nEdges);

    // 4) atomic-free partition into bucket regions (single uint2 array)
    partition_edges2<<<nTiles, PT2, 0, stream>>>(row, col, vals, bases,
                                                 tileCnt, cv, nEdges, NB);

    // 5) per bucket-half LDS-staged counting sort -> exact CSR
    csr_sort4<<<2 * NB, 512, 0, stream>>>(bases, cv, cv2, rowptr, n, nEdges);

    // 6) xq = int8(emb / (embMax/127))   (cv region is dead now)
    quant8_f32<<<(nElem + BLK - 1) / BLK, BLK, 0, stream>>>(emb, &scal[0], xq, nElem);

    // 7) layer 1: int32 accumulate, y1h + y1Max
    int rowBlocks = (n * 32 + BLK - 1) / BLK;
    spmm_l1_q8<<<rowBlocks, BLK, 0, stream>>>(rowptr, cv2, xq, &scal[0],
                                              y1h, &scal[1], n);

    // 8) y1q = int8(y1h / (y1Max/127))
    quant8_bf16<<<(nElem + BLK - 1) / BLK, BLK, 0, stream>>>(y1h, &scal[1], y1q, nElem);

    // 9) out = (E + y1 + A*y1)/3
    spmm_combine_q8<<<rowBlocks, BLK, 0, stream>>>(rowptr, cv2, y1q, &scal[1],
                                                   y1h, emb, out, n);
}

// Round 16
// 249.352 us; speedup vs baseline: 1.4565x; 1.4565x over previous
//
#include <hip/hip_runtime.h>

// DyHuCoG: out = (E + A*E + A*(A*E)) / 3
// E: [N,32] f32, A: COO (vals f32, row i32, col i32), N=100001, nE=6400000.
//
// Pipeline (atomic-free partition, 4B edges, dword-gather SpMM):
//   1) tile_hist: per-4096-edge tile bucket histogram (256-row buckets)
//   2) colscan:   in-place exclusive scan down each bucket column
//   3) scan_buckets: bucket bases
//   4) partition_edges2: LDS counting-sort per tile (NO global atomics),
//      coalesced run writes of ONE uint2 array {col|rowlow<<17, q15 val}
//   5) csr_sort4: per bucket-half LDS-staged counting sort -> exact CSR
//   6) cast emb -> bf16 (packed pairs)
//   7) spmm_l1: 16 lanes/row, 1 dword = 2 bf16 per gather (halves VMEM
//      instructions + address VALU per edge), y1h = bf16(A*E)
//   8) spmm_combine: out = (E + y1 + A*y1)/3, float2 I/O

constexpr int D = 32;
constexpr int RPB_LOG = 8;               // rows per bucket = 256
constexpr int RPB = 1 << RPB_LOG;
constexpr int MAXNB = 512;               // supports n <= 131072 (17-bit col)
constexpr int TILE = 4096;               // edges per partition tile
constexpr int PT2 = 512;                 // partition threads
constexpr int CAP = 9728;                // LDS staging capacity (edges/half)
constexpr float QSCALE = 32768.0f;       // 15-bit val quantization
constexpr float QINV = 1.0f / 32768.0f;

__device__ __forceinline__ unsigned short f2bf(float f) {
    unsigned u = __float_as_uint(f);
    unsigned r = (u + 0x7FFFu + ((u >> 16) & 1u)) >> 16;   // RNE
    return (unsigned short)r;
}
__device__ __forceinline__ float bf2f(unsigned short h) {
    return __uint_as_float((unsigned)h << 16);
}
__device__ __forceinline__ float lo_f(unsigned v) {       // bf16 pair low
    return __uint_as_float(v << 16);
}
__device__ __forceinline__ float hi_f(unsigned v) {       // bf16 pair high
    return __uint_as_float(v & 0xFFFF0000u);
}

__global__ void zero_f32(float* __restrict__ p, int n) {
    int i = blockIdx.x * blockDim.x + threadIdx.x;
    if (i < n) p[i] = 0.0f;
}
__global__ void cast_bf16(const float* __restrict__ in,
                          unsigned short* __restrict__ out, int n) {
    int i = blockIdx.x * blockDim.x + threadIdx.x;
    if (i < n) out[i] = f2bf(in[i]);
}

// ------- 1) per-tile bucket histogram -> tileCnt[tile][NB] (coalesced) ----
__global__ __launch_bounds__(256) void tile_hist(
    const int* __restrict__ row, int* __restrict__ tileCnt, int nE, int NB) {
    __shared__ int h[MAXNB];
    int tile = blockIdx.x;
    int base = tile * TILE;
    int n = min(TILE, nE - base);
    int t = threadIdx.x;
    for (int i = t; i < NB; i += 256) h[i] = 0;
    __syncthreads();
    for (int i = t; i < n; i += 256)
        atomicAdd(&h[row[base + i] >> RPB_LOG], 1);
    __syncthreads();
    for (int i = t; i < NB; i += 256)
        tileCnt[(size_t)tile * NB + i] = h[i];
}

// ------- 2) in-place exclusive column scan + bucket totals ---------------
__global__ __launch_bounds__(256) void colscan(
    int* __restrict__ tileCnt, int* __restrict__ cnt, int nTiles, int NB) {
    __shared__ int s2[256];
    __shared__ int carryS;
    int b = blockIdx.x, t = threadIdx.x;
    if (t == 0) carryS = 0;
    __syncthreads();
    for (int c0 = 0; c0 < nTiles; c0 += 1024) {
        int v[4], idx[4];
        int sum = 0;
#pragma unroll
        for (int k = 0; k < 4; ++k) {
            idx[k] = c0 + t * 4 + k;
            v[k] = (idx[k] < nTiles) ? tileCnt[(size_t)idx[k] * NB + b] : 0;
            sum += v[k];
        }
        s2[t] = sum;
        __syncthreads();
        for (int o = 1; o < 256; o <<= 1) {
            int x = (t >= o) ? s2[t - o] : 0;
            __syncthreads();
            s2[t] += x;
            __syncthreads();
        }
        int run = ((t == 0) ? 0 : s2[t - 1]) + carryS;
#pragma unroll
        for (int k = 0; k < 4; ++k) {
            if (idx[k] < nTiles) tileCnt[(size_t)idx[k] * NB + b] = run;
            run += v[k];
        }
        __syncthreads();
        if (t == 0) carryS += s2[255];
        __syncthreads();
    }
    if (t == 0) cnt[b] = carryS;
}

// ---------------- 3) exclusive scan of bucket counts (NB <= 512) ---------
__global__ __launch_bounds__(512) void scan_buckets(
    const int* __restrict__ cnt, int* __restrict__ bases, int NB, int nE) {
    __shared__ int s[MAXNB];
    int t = threadIdx.x;
    s[t] = (t < NB) ? cnt[t] : 0;
    __syncthreads();
    for (int o = 1; o < 512; o <<= 1) {
        int v = (t >= o) ? s[t - o] : 0;
        __syncthreads();
        s[t] += v;
        __syncthreads();
    }
    if (t < NB) bases[t] = (t == 0) ? 0 : s[t - 1];
    if (t == 0) bases[NB] = nE;
}

// ------- 4) tiled partition, NO global atomics, coalesced writes ---------
__global__ __launch_bounds__(PT2) void partition_edges2(
    const int* __restrict__ row, const int* __restrict__ col,
    const float* __restrict__ vals, const int* __restrict__ bases,
    const int* __restrict__ tileCnt, uint2* __restrict__ cv, int nE, int NB) {
    __shared__ uint2 buf[TILE];            // 32 KB
    __shared__ unsigned short bkt[TILE];   // 8 KB
    __shared__ int hist[MAXNB];            // 2 KB (-> runbase - runoff0)
    __shared__ int runoff[MAXNB];          // 2 KB (local excl scan -> cursor)
    __shared__ int s2[PT2];                // 2 KB
    int t = threadIdx.x;
    int tile = blockIdx.x;
    int base = tile * TILE;
    int n = min(TILE, nE - base);
    if (n <= 0) return;
    for (int i = t; i < NB; i += PT2) hist[i] = 0;
    __syncthreads();
    for (int i = t; i < n; i += PT2)
        atomicAdd(&hist[row[base + i] >> RPB_LOG], 1);
    __syncthreads();
    // local exclusive scan of hist -> runoff (1 elem/thread covers 512)
    {
        int a0 = (t < NB) ? hist[t] : 0;
        s2[t] = a0;
        __syncthreads();
        for (int o = 1; o < PT2; o <<= 1) {
            int v = (t >= o) ? s2[t - o] : 0;
            __syncthreads();
            s2[t] += v;
            __syncthreads();
        }
        if (t < NB) runoff[t] = s2[t] - a0;   // exclusive
    }
    __syncthreads();
    // hist[b] := global run base - runoff0[b]
    for (int i = t; i < NB; i += PT2)
        hist[i] = bases[i] + tileCnt[(size_t)tile * NB + i] - runoff[i];
    __syncthreads();
    // reorder into LDS bucket-major
    for (int i = t; i < n; i += PT2) {
        int r = row[base + i];
        int b = r >> RPB_LOG;
        int slot = atomicAdd(&runoff[b], 1);
        float v = vals[base + i];
        int q = __float2int_rn(v * QSCALE);
        q = max(0, min(32767, q));
        uint2 p;
        p.x = (unsigned)col[base + i] | ((unsigned)(r & (RPB - 1)) << 17);
        p.y = (unsigned)q;
        buf[slot] = p;
        bkt[slot] = (unsigned short)b;
    }
    __syncthreads();
    // coalesced run writes: dest = hist[b] + slot (slot == i)
    for (int i = t; i < n; i += PT2)
        cv[hist[bkt[i]] + i] = buf[i];
}

// ------- 5) per bucket-half LDS-staged counting sort -> exact CSR --------
__global__ __launch_bounds__(512) void csr_sort4(
    const int* __restrict__ bases, const uint2* __restrict__ cv,
    unsigned* __restrict__ cv2, int* __restrict__ rowptr, int n, int nE) {
    __shared__ unsigned stage[CAP];        // 38 KB
    __shared__ int hist_s[RPB];            // 1 KB
    __shared__ int cur_s[RPB];             // 1 KB
    int t = threadIdx.x;
    int b = blockIdx.x >> 1;
    int h = blockIdx.x & 1;
    int s = bases[b], e = bases[b + 1];
    if (t < RPB) hist_s[t] = 0;
    __syncthreads();
    for (int i = s + t; i < e; i += 512)
        atomicAdd(&hist_s[cv[i].x >> 17], 1);
    __syncthreads();
    if (t < RPB) cur_s[t] = hist_s[t];
    __syncthreads();
    for (int o = 1; o < RPB; o <<= 1) {       // inclusive scan
        int v = 0;
        if (t < RPB && t >= o) v = cur_s[t - o];
        __syncthreads();
        if (t < RPB) cur_s[t] += v;
        __syncthreads();
    }
    int excl = 0;
    if (t < RPB) excl = (t == 0) ? 0 : cur_s[t - 1];
    int half_lo = h << 7;                     // h*128
    __syncthreads();
    int base_h = (half_lo == 0) ? 0 : cur_s[half_lo - 1];
    int end_h  = cur_s[half_lo + 127];
    int cnt_h  = end_h - base_h;
    __syncthreads();
    if (t < RPB) {
        if ((t >> 7) == h) {
            int r = (b << RPB_LOG) + t;
            if (r < n) rowptr[r] = s + excl;
            cur_s[t] = excl - base_h;         // local staging cursor
        }
    }
    if (b == 0 && h == 0 && t == 0) rowptr[n] = nE;
    __syncthreads();
    bool fits = (cnt_h <= CAP);
    for (int i = s + t; i < e; i += 512) {
        uint2 p = cv[i];
        int r = (int)(p.x >> 17);
        if ((r >> 7) != h) continue;
        int slot = atomicAdd(&cur_s[r], 1);
        unsigned packed = (p.x & 0x1FFFFu) | (p.y << 17);
        if (fits) stage[slot] = packed;
        else      cv2[s + base_h + slot] = packed;
    }
    __syncthreads();
    if (fits) {
        int dst = s + base_h;
        for (int j = t; j < cnt_h; j += 512)
            cv2[dst + j] = stage[j];
    }
}

// ---- 7) layer-1 SpMM: 16 lanes/row, dword gathers, y1h = bf16(A*E) ------
// xd: emb as packed bf16 pairs (16 dwords/row); yd: y1 bf16 pairs out.
__global__ __launch_bounds__(256) void spmm_l1(
    const int* __restrict__ ptr, const unsigned* __restrict__ cv,
    const unsigned* __restrict__ xd, unsigned* __restrict__ yd, int nRows) {
    int g = (blockIdx.x * 256 + threadIdx.x) >> 4;
    if (g >= nRows) return;
    int lane = threadIdx.x & 15;
    int e = ptr[g], end = ptr[g + 1];
    float a0 = 0.0f, a1 = 0.0f;
    for (; e + 8 <= end; e += 8) {
        unsigned q0 = cv[e], q1 = cv[e + 1], q2 = cv[e + 2], q3 = cv[e + 3];
        unsigned q4 = cv[e + 4], q5 = cv[e + 5], q6 = cv[e + 6], q7 = cv[e + 7];
        unsigned v0 = xd[(size_t)(q0 & 0x1FFFFu) * 16 + lane];
        unsigned v1 = xd[(size_t)(q1 & 0x1FFFFu) * 16 + lane];
        unsigned v2 = xd[(size_t)(q2 & 0x1FFFFu) * 16 + lane];
        unsigned v3 = xd[(size_t)(q3 & 0x1FFFFu) * 16 + lane];
        unsigned v4 = xd[(size_t)(q4 & 0x1FFFFu) * 16 + lane];
        unsigned v5 = xd[(size_t)(q5 & 0x1FFFFu) * 16 + lane];
        unsigned v6 = xd[(size_t)(q6 & 0x1FFFFu) * 16 + lane];
        unsigned v7 = xd[(size_t)(q7 & 0x1FFFFu) * 16 + lane];
        float s0 = (float)(q0 >> 17), s1 = (float)(q1 >> 17);
        float s2 = (float)(q2 >> 17), s3 = (float)(q3 >> 17);
        float s4 = (float)(q4 >> 17), s5 = (float)(q5 >> 17);
        float s6 = (float)(q6 >> 17), s7 = (float)(q7 >> 17);
        a0 += s0 * lo_f(v0);  a1 += s0 * hi_f(v0);
        a0 += s1 * lo_f(v1);  a1 += s1 * hi_f(v1);
        a0 += s2 * lo_f(v2);  a1 += s2 * hi_f(v2);
        a0 += s3 * lo_f(v3);  a1 += s3 * hi_f(v3);
        a0 += s4 * lo_f(v4);  a1 += s4 * hi_f(v4);
        a0 += s5 * lo_f(v5);  a1 += s5 * hi_f(v5);
        a0 += s6 * lo_f(v6);  a1 += s6 * hi_f(v6);
        a0 += s7 * lo_f(v7);  a1 += s7 * hi_f(v7);
    }
    for (; e < end; ++e) {
        unsigned q = cv[e];
        unsigned v = xd[(size_t)(q & 0x1FFFFu) * 16 + lane];
        float s = (float)(q >> 17);
        a0 += s * lo_f(v);
        a1 += s * hi_f(v);
    }
    unsigned packed = (unsigned)f2bf(a0 * QINV) |
                      ((unsigned)f2bf(a1 * QINV) << 16);
    yd[(size_t)g * 16 + lane] = packed;
}

// ---- 8) layer-2 SpMM fused combine: out = (E + y1 + A*y1)/3, float2 -----
__global__ __launch_bounds__(256) void spmm_combine(
    const int* __restrict__ ptr, const unsigned* __restrict__ cv,
    const unsigned* __restrict__ yd, const float2* __restrict__ emb2,
    float2* __restrict__ out2, int nRows) {
    int g = (blockIdx.x * 256 + threadIdx.x) >> 4;
    if (g >= nRows) return;
    int lane = threadIdx.x & 15;
    int e = ptr[g], end = ptr[g + 1];
    float a0 = 0.0f, a1 = 0.0f;
    for (; e + 8 <= end; e += 8) {
        unsigned q0 = cv[e], q1 = cv[e + 1], q2 = cv[e + 2], q3 = cv[e + 3];
        unsigned q4 = cv[e + 4], q5 = cv[e + 5], q6 = cv[e + 6], q7 = cv[e + 7];
        unsigned v0 = yd[(size_t)(q0 & 0x1FFFFu) * 16 + lane];
        unsigned v1 = yd[(size_t)(q1 & 0x1FFFFu) * 16 + lane];
        unsigned v2 = yd[(size_t)(q2 & 0x1FFFFu) * 16 + lane];
        unsigned v3 = yd[(size_t)(q3 & 0x1FFFFu) * 16 + lane];
        unsigned v4 = yd[(size_t)(q4 & 0x1FFFFu) * 16 + lane];
        unsigned v5 = yd[(size_t)(q5 & 0x1FFFFu) * 16 + lane];
        unsigned v6 = yd[(size_t)(q6 & 0x1FFFFu) * 16 + lane];
        unsigned v7 = yd[(size_t)(q7 & 0x1FFFFu) * 16 + lane];
        float s0 = (float)(q0 >> 17), s1 = (float)(q1 >> 17);
        float s2 = (float)(q2 >> 17), s3 = (float)(q3 >> 17);
        float s4 = (float)(q4 >> 17), s5 = (float)(q5 >> 17);
        float s6 = (float)(q6 >> 17), s7 = (float)(q7 >> 17);
        a0 += s0 * lo_f(v0);  a1 += s0 * hi_f(v0);
        a0 += s1 * lo_f(v1);  a1 += s1 * hi_f(v1);
        a0 += s2 * lo_f(v2);  a1 += s2 * hi_f(v2);
        a0 += s3 * lo_f(v3);  a1 += s3 * hi_f(v3);
        a0 += s4 * lo_f(v4);  a1 += s4 * hi_f(v4);
        a0 += s5 * lo_f(v5);  a1 += s5 * hi_f(v5);
        a0 += s6 * lo_f(v6);  a1 += s6 * hi_f(v6);
        a0 += s7 * lo_f(v7);  a1 += s7 * hi_f(v7);
    }
    for (; e < end; ++e) {
        unsigned q = cv[e];
        unsigned v = yd[(size_t)(q & 0x1FFFFu) * 16 + lane];
        float s = (float)(q >> 17);
        a0 += s * lo_f(v);
        a1 += s * hi_f(v);
    }
    size_t idx = (size_t)g * 16 + lane;
    float2 eb = emb2[idx];
    unsigned yv = yd[idx];
    float2 r;
    r.x = (eb.x + lo_f(yv) + a0 * QINV) * (1.0f / 3.0f);
    r.y = (eb.y + hi_f(yv) + a1 * QINV) * (1.0f / 3.0f);
    out2[idx] = r;
}

// =================== atomic fallback ===================
__global__ __launch_bounds__(256) void spmm_atomic(
    const int* __restrict__ row, const int* __restrict__ col,
    const float* __restrict__ vals, const float* __restrict__ x,
    float* __restrict__ y, int nEdges, float scale) {
    long long t = (long long)blockIdx.x * blockDim.x + threadIdx.x;
    int e = (int)(t >> 5);
    if (e >= nEdges) return;
    int d = (int)(t & 31);
    float g = vals[e] * scale * x[(long long)col[e] * D + d];
    atomicAdd(&y[(long long)row[e] * D + d], g);
}
__global__ void combine_third(const float* __restrict__ emb,
                              const float* __restrict__ y1,
                              float* __restrict__ out, int n) {
    int i = blockIdx.x * blockDim.x + threadIdx.x;
    if (i < n) out[i] = (emb[i] + y1[i]) * (1.0f / 3.0f);
}

extern "C" void kernel_launch(void* const* d_in, const int* in_sizes, int n_in,
                              void* d_out, int out_size, void* d_ws, size_t ws_size,
                              hipStream_t stream) {
    const float* emb  = (const float*)d_in[0];
    const float* vals = (const float*)d_in[1];
    const int*   row  = (const int*)d_in[2];
    const int*   col  = (const int*)d_in[3];
    float* out = (float*)d_out;

    const int nElem  = in_sizes[0];          // N * 32
    const int nEdges = in_sizes[1];
    const int n      = nElem / D;            // 100001
    const int NB     = (n + RPB - 1) >> RPB_LOG;   // 391
    const int BLK = 256;
    const int nTiles = (nEdges + TILE - 1) / TILE; // 1563

    // workspace layout:
    //   misc | cv(uint2 8B*nE) | cv2(u32 4B*nE)
    //   tileCnt aliases cv2 (dead before csr_sort4 writes cv2)
    //   y1h/embh alias cv (dead after csr_sort4)
    size_t off_cnt    = 0;                                    // NB ints
    size_t off_bases  = off_cnt + (size_t)NB * 4;             // NB+1 ints
    size_t off_rowptr = off_bases + (size_t)(NB + 1) * 4;     // n+1 ints
    size_t off_cv     = (off_rowptr + (size_t)(n + 1) * 4 + 63) & ~(size_t)63;
    size_t off_cv2    = off_cv + (size_t)nEdges * 8;
    size_t need       = off_cv2 + (size_t)nEdges * 4;

    bool aliasFit   = ((size_t)nElem * 4 <= (size_t)nEdges * 8);   // y1h+embh in cv
    bool tileCntFit = ((size_t)nTiles * NB * 4 <= (size_t)nEdges * 4);
    bool ok = (NB <= MAXNB) && (n <= 131072) && (ws_size >= need) &&
              aliasFit && tileCntFit;

    if (!ok) {
        // fallback: atomic-scatter path (needs nElem floats)
        if (ws_size < (size_t)nElem * 4) return;
        float* y1 = (float*)d_ws;
        zero_f32<<<(nElem + BLK - 1) / BLK, BLK, 0, stream>>>(y1, nElem);
        long long threads = (long long)nEdges * 32;
        int blocks = (int)((threads + BLK - 1) / BLK);
        spmm_atomic<<<blocks, BLK, 0, stream>>>(row, col, vals, emb, y1, nEdges, 1.0f);
        combine_third<<<(nElem + BLK - 1) / BLK, BLK, 0, stream>>>(emb, y1, out, nElem);
        spmm_atomic<<<blocks, BLK, 0, stream>>>(row, col, vals, y1, out, nEdges, 1.0f / 3.0f);
        return;
    }

    char* ws = (char*)d_ws;
    int*            cnt     = (int*)(ws + off_cnt);
    int*            bases   = (int*)(ws + off_bases);
    int*            rowptr  = (int*)(ws + off_rowptr);
    uint2*          cv      = (uint2*)(ws + off_cv);
    unsigned*       cv2     = (unsigned*)(ws + off_cv2);
    int*            tileCnt = (int*)(ws + off_cv2);           // alias
    unsigned*       yd      = (unsigned*)(ws + off_cv);       // y1 bf16 pairs
    unsigned short* embh    = (unsigned short*)(ws + off_cv + (size_t)nElem * 2);
    unsigned*       xd      = (unsigned*)embh;                // emb bf16 pairs

    // 1) per-tile histograms
    tile_hist<<<nTiles, 256, 0, stream>>>(row, tileCnt, nEdges, NB);

    // 2) column scan (in-place) + bucket totals
    colscan<<<NB, 256, 0, stream>>>(tileCnt, cnt, nTiles, NB);

    // 3) bucket bases
    scan_buckets<<<1, 512, 0, stream>>>(cnt, bases, NB, nEdges);

    // 4) atomic-free partition into bucket regions (single uint2 array)
    partition_edges2<<<nTiles, PT2, 0, stream>>>(row, col, vals, bases,
                                                 tileCnt, cv, nEdges, NB);

    // 5) per bucket-half LDS-staged counting sort -> exact CSR
    csr_sort4<<<2 * NB, 512, 0, stream>>>(bases, cv, cv2, rowptr, n, nEdges);

    // 6) embh = bf16(emb)   (cv region is dead now)
    cast_bf16<<<(nElem + BLK - 1) / BLK, BLK, 0, stream>>>(emb, embh, nElem);

    // 7) y1 = A*E  (16 lanes/row, dword gathers)
    int rowBlocks = (n * 16 + BLK - 1) / BLK;
    spmm_l1<<<rowBlocks, BLK, 0, stream>>>(rowptr, cv2, xd, yd, n);

    // 8) out = (E + y1 + A*y1)/3
    spmm_combine<<<rowBlocks, BLK, 0, stream>>>(rowptr, cv2, yd,
                                                (const float2*)emb,
                                                (float2*)out, n);
}

// Round 17
// 246.528 us; speedup vs baseline: 1.4732x; 1.0115x over previous
//
#include <hip/hip_runtime.h>

// DyHuCoG: out = (E + A*E + A*(A*E)) / 3
// E: [N,32] f32, A: COO (vals f32, row i32, col i32), N=100001, nE=6400000.
//
// Pipeline (atomic-free partition, 4B edges, col-split L2-resident SpMM
// with LDS-staged coalesced sorter):
//   1) tile_hist: per-4096-edge tile bucket histogram (256-row buckets)
//   2) colscan:   in-place exclusive scan down each bucket column
//   3) scan_buckets: bucket bases
//   4) partition_edges2: LDS counting-sort per tile (NO global atomics);
//      bucket id packed into val word (no bkt[] array -> 38KB LDS, 4 blk/CU)
//   5) csr_sort5: per bucket-half, 512-key (rowlow, col>=half) LDS-staged
//      counting sort -> cv2 (4B/edge) + rowptr2[2n+1]; writes coalesced
//   6) cast emb -> bf16 pairs
//   7) layer1 in 2 phases (lo/hi cols, 3.2MB gather set each, L2-resident):
//      phase0 -> f32 partial, phase1 -> yd = bf16 pairs of y1
//   8) layer2 same, phase1 fused with final combine

constexpr int D = 32;
constexpr int RPB_LOG = 8;               // rows per bucket = 256
constexpr int RPB = 1 << RPB_LOG;
constexpr int KEYS = 2 * RPB;            // (rowlow, colhalf) keys = 512
constexpr int MAXNB = 512;               // supports n <= 131072 (17-bit col)
constexpr int TILE = 4096;               // edges per partition tile
constexpr int PT2 = 512;                 // partition threads
constexpr int CAP = 9216;                // LDS staging capacity (edges/half)
constexpr float QSCALE = 32768.0f;       // 15-bit val quantization
constexpr float QINV = 1.0f / 32768.0f;

__device__ __forceinline__ unsigned short f2bf(float f) {
    unsigned u = __float_as_uint(f);
    unsigned r = (u + 0x7FFFu + ((u >> 16) & 1u)) >> 16;   // RNE
    return (unsigned short)r;
}
__device__ __forceinline__ float lo_f(unsigned v) {       // bf16 pair low
    return __uint_as_float(v << 16);
}
__device__ __forceinline__ float hi_f(unsigned v) {       // bf16 pair high
    return __uint_as_float(v & 0xFFFF0000u);
}

__global__ void zero_f32(float* __restrict__ p, int n) {
    int i = blockIdx.x * blockDim.x + threadIdx.x;
    if (i < n) p[i] = 0.0f;
}
__global__ void cast_bf16(const float* __restrict__ in,
                          unsigned short* __restrict__ out, int n) {
    int i = blockIdx.x * blockDim.x + threadIdx.x;
    if (i < n) out[i] = f2bf(in[i]);
}

// ------- 1) per-tile bucket histogram -> tileCnt[tile][NB] (coalesced) ----
__global__ __launch_bounds__(256) void tile_hist(
    const int* __restrict__ row, int* __restrict__ tileCnt, int nE, int NB) {
    __shared__ int h[MAXNB];
    int tile = blockIdx.x;
    int base = tile * TILE;
    int n = min(TILE, nE - base);
    int t = threadIdx.x;
    for (int i = t; i < NB; i += 256) h[i] = 0;
    __syncthreads();
    for (int i = t; i < n; i += 256)
        atomicAdd(&h[row[base + i] >> RPB_LOG], 1);
    __syncthreads();
    for (int i = t; i < NB; i += 256)
        tileCnt[(size_t)tile * NB + i] = h[i];
}

// ------- 2) in-place exclusive column scan + bucket totals ---------------
__global__ __launch_bounds__(256) void colscan(
    int* __restrict__ tileCnt, int* __restrict__ cnt, int nTiles, int NB) {
    __shared__ int s2[256];
    __shared__ int carryS;
    int b = blockIdx.x, t = threadIdx.x;
    if (t == 0) carryS = 0;
    __syncthreads();
    for (int c0 = 0; c0 < nTiles; c0 += 1024) {
        int v[4], idx[4];
        int sum = 0;
#pragma unroll
        for (int k = 0; k < 4; ++k) {
            idx[k] = c0 + t * 4 + k;
            v[k] = (idx[k] < nTiles) ? tileCnt[(size_t)idx[k] * NB + b] : 0;
            sum += v[k];
        }
        s2[t] = sum;
        __syncthreads();
        for (int o = 1; o < 256; o <<= 1) {
            int x = (t >= o) ? s2[t - o] : 0;
            __syncthreads();
            s2[t] += x;
            __syncthreads();
        }
        int run = ((t == 0) ? 0 : s2[t - 1]) + carryS;
#pragma unroll
        for (int k = 0; k < 4; ++k) {
            if (idx[k] < nTiles) tileCnt[(size_t)idx[k] * NB + b] = run;
            run += v[k];
        }
        __syncthreads();
        if (t == 0) carryS += s2[255];
        __syncthreads();
    }
    if (t == 0) cnt[b] = carryS;
}

// ---------------- 3) exclusive scan of bucket counts (NB <= 512) ---------
__global__ __launch_bounds__(512) void scan_buckets(
    const int* __restrict__ cnt, int* __restrict__ bases, int NB, int nE) {
    __shared__ int s[MAXNB];
    int t = threadIdx.x;
    s[t] = (t < NB) ? cnt[t] : 0;
    __syncthreads();
    for (int o = 1; o < 512; o <<= 1) {
        int v = (t >= o) ? s[t - o] : 0;
        __syncthreads();
        s[t] += v;
        __syncthreads();
    }
    if (t < NB) bases[t] = (t == 0) ? 0 : s[t - 1];
    if (t == 0) bases[NB] = nE;
}

// ------- 4) tiled partition, NO global atomics, coalesced writes ---------
// val word packs q15 | bucket<<15 (stripped by csr_sort5).
__global__ __launch_bounds__(PT2) void partition_edges2(
    const int* __restrict__ row, const int* __restrict__ col,
    const float* __restrict__ vals, const int* __restrict__ bases,
    const int* __restrict__ tileCnt, uint2* __restrict__ cv, int nE, int NB) {
    __shared__ uint2 buf[TILE];            // 32 KB
    __shared__ int hist[MAXNB];            // 2 KB (-> runbase - runoff0)
    __shared__ int runoff[MAXNB];          // 2 KB (local excl scan -> cursor)
    __shared__ int s2[PT2];                // 2 KB
    int t = threadIdx.x;
    int tile = blockIdx.x;
    int base = tile * TILE;
    int n = min(TILE, nE - base);
    if (n <= 0) return;
    for (int i = t; i < NB; i += PT2) hist[i] = 0;
    __syncthreads();
    for (int i = t; i < n; i += PT2)
        atomicAdd(&hist[row[base + i] >> RPB_LOG], 1);
    __syncthreads();
    // local exclusive scan of hist -> runoff (1 elem/thread covers 512)
    {
        int a0 = (t < NB) ? hist[t] : 0;
        s2[t] = a0;
        __syncthreads();
        for (int o = 1; o < PT2; o <<= 1) {
            int v = (t >= o) ? s2[t - o] : 0;
            __syncthreads();
            s2[t] += v;
            __syncthreads();
        }
        if (t < NB) runoff[t] = s2[t] - a0;   // exclusive
    }
    __syncthreads();
    // hist[b] := global run base - runoff0[b]
    for (int i = t; i < NB; i += PT2)
        hist[i] = bases[i] + tileCnt[(size_t)tile * NB + i] - runoff[i];
    __syncthreads();
    // reorder into LDS bucket-major; bucket id packed in y bits 15..23
    for (int i = t; i < n; i += PT2) {
        int r = row[base + i];
        int b = r >> RPB_LOG;
        int slot = atomicAdd(&runoff[b], 1);
        float v = vals[base + i];
        int q = __float2int_rn(v * QSCALE);
        q = max(0, min(32767, q));
        uint2 p;
        p.x = (unsigned)col[base + i] | ((unsigned)(r & (RPB - 1)) << 17);
        p.y = (unsigned)q | ((unsigned)b << 15);
        buf[slot] = p;
    }
    __syncthreads();
    // coalesced run writes: dest = hist[b] + slot (slot == i)
    for (int i = t; i < n; i += PT2) {
        uint2 v = buf[i];
        cv[hist[v.y >> 15] + i] = v;
    }
}

// ---- 5) per bucket-half 512-key LDS-staged sort -> cv2 + rowptr2 --------
// key = rowlow<<1 | (col>=half). Block (b,h) emits keys [h*256,(h+1)*256).
__global__ __launch_bounds__(512) void csr_sort5(
    const int* __restrict__ bases, const uint2* __restrict__ cv,
    unsigned* __restrict__ cv2, int* __restrict__ rowptr2,
    int n, int nE, int half) {
    __shared__ unsigned stage[CAP];        // 36 KB
    __shared__ int hist_s[KEYS];           // 2 KB
    __shared__ int cur_s[KEYS];            // 2 KB
    int t = threadIdx.x;
    int b = blockIdx.x >> 1;
    int h = blockIdx.x & 1;
    int s = bases[b], e = bases[b + 1];
    hist_s[t] = 0;
    __syncthreads();
    // pass 1: full-bucket 512-key histogram
    for (int i = s + t; i < e; i += 512) {
        uint2 p = cv[i];
        int key = (int)((p.x >> 17) << 1) |
                  (((int)(p.x & 0x1FFFFu) >= half) ? 1 : 0);
        atomicAdd(&hist_s[key], 1);
    }
    __syncthreads();
    cur_s[t] = hist_s[t];
    __syncthreads();
    for (int o = 1; o < KEYS; o <<= 1) {       // inclusive scan
        int v = (t >= o) ? cur_s[t - o] : 0;
        __syncthreads();
        cur_s[t] += v;
        __syncthreads();
    }
    int excl = (t == 0) ? 0 : cur_s[t - 1];
    __syncthreads();
    int kh = h << 8;                           // h*256
    int base_h = (kh == 0) ? 0 : cur_s[kh - 1];
    int end_h  = cur_s[kh + 255];
    int cnt_h  = end_h - base_h;
    __syncthreads();
    // rowptr2 + staging cursors for own keys
    if ((t >> 8) == h) {
        int r = (b << RPB_LOG) + (t >> 1);
        if (r < n) rowptr2[((size_t)r << 1) | (t & 1)] = s + excl;
        cur_s[t] = excl - base_h;              // local staging cursor
    }
    if (b == 0 && h == 0 && t == 0) rowptr2[2 * n] = nE;
    __syncthreads();
    bool fits = (cnt_h <= CAP);
    // pass 2: re-read, keep own keys, stage (or direct-scatter on overflow)
    for (int i = s + t; i < e; i += 512) {
        uint2 p = cv[i];
        int key = (int)((p.x >> 17) << 1) |
                  (((int)(p.x & 0x1FFFFu) >= half) ? 1 : 0);
        if ((key >> 8) != h) continue;
        int slot = atomicAdd(&cur_s[key], 1);
        unsigned packed = (p.x & 0x1FFFFu) | ((p.y & 0x7FFFu) << 17);
        if (fits) stage[slot] = packed;
        else      cv2[s + base_h + slot] = packed;
    }
    __syncthreads();
    // pass 3: coalesced run write
    if (fits) {
        int dst = s + base_h;
        for (int j = t; j < cnt_h; j += 512)
            cv2[dst + j] = stage[j];
    }
}

// ---- 7) layer-1 SpMM, 2 phases, 16 lanes/row, dword gathers -------------
template <int PHASE>
__global__ __launch_bounds__(256) void spmm_l1(
    const int* __restrict__ ptr2, const unsigned* __restrict__ cv,
    const unsigned* __restrict__ xd, float2* __restrict__ part,
    unsigned* __restrict__ yd, int nRows) {
    int g = (blockIdx.x * 256 + threadIdx.x) >> 4;
    if (g >= nRows) return;
    int lane = threadIdx.x & 15;
    int e = ptr2[2 * g + PHASE], end = ptr2[2 * g + PHASE + 1];
    float a0 = 0.0f, a1 = 0.0f;
    for (; e + 8 <= end; e += 8) {
        unsigned q0 = cv[e], q1 = cv[e + 1], q2 = cv[e + 2], q3 = cv[e + 3];
        unsigned q4 = cv[e + 4], q5 = cv[e + 5], q6 = cv[e + 6], q7 = cv[e + 7];
        unsigned v0 = xd[(size_t)(q0 & 0x1FFFFu) * 16 + lane];
        unsigned v1 = xd[(size_t)(q1 & 0x1FFFFu) * 16 + lane];
        unsigned v2 = xd[(size_t)(q2 & 0x1FFFFu) * 16 + lane];
        unsigned v3 = xd[(size_t)(q3 & 0x1FFFFu) * 16 + lane];
        unsigned v4 = xd[(size_t)(q4 & 0x1FFFFu) * 16 + lane];
        unsigned v5 = xd[(size_t)(q5 & 0x1FFFFu) * 16 + lane];
        unsigned v6 = xd[(size_t)(q6 & 0x1FFFFu) * 16 + lane];
        unsigned v7 = xd[(size_t)(q7 & 0x1FFFFu) * 16 + lane];
        float s0 = (float)(q0 >> 17), s1 = (float)(q1 >> 17);
        float s2 = (float)(q2 >> 17), s3 = (float)(q3 >> 17);
        float s4 = (float)(q4 >> 17), s5 = (float)(q5 >> 17);
        float s6 = (float)(q6 >> 17), s7 = (float)(q7 >> 17);
        a0 += s0 * lo_f(v0);  a1 += s0 * hi_f(v0);
        a0 += s1 * lo_f(v1);  a1 += s1 * hi_f(v1);
        a0 += s2 * lo_f(v2);  a1 += s2 * hi_f(v2);
        a0 += s3 * lo_f(v3);  a1 += s3 * hi_f(v3);
        a0 += s4 * lo_f(v4);  a1 += s4 * hi_f(v4);
        a0 += s5 * lo_f(v5);  a1 += s5 * hi_f(v5);
        a0 += s6 * lo_f(v6);  a1 += s6 * hi_f(v6);
        a0 += s7 * lo_f(v7);  a1 += s7 * hi_f(v7);
    }
    for (; e < end; ++e) {
        unsigned q = cv[e];
        unsigned v = xd[(size_t)(q & 0x1FFFFu) * 16 + lane];
        float s = (float)(q >> 17);
        a0 += s * lo_f(v);
        a1 += s * hi_f(v);
    }
    size_t idx = (size_t)g * 16 + lane;
    if (PHASE == 0) {
        part[idx] = make_float2(a0, a1);
    } else {
        float2 p = part[idx];
        unsigned packed = (unsigned)f2bf((p.x + a0) * QINV) |
                          ((unsigned)f2bf((p.y + a1) * QINV) << 16);
        yd[idx] = packed;
    }
}

// ---- 8) layer-2 SpMM, 2 phases, phase 1 fused with combine --------------
template <int PHASE>
__global__ __launch_bounds__(256) void spmm_l2(
    const int* __restrict__ ptr2, const unsigned* __restrict__ cv,
    const unsigned* __restrict__ yd, const float2* __restrict__ emb2,
    float2* __restrict__ part, float2* __restrict__ out2, int nRows) {
    int g = (blockIdx.x * 256 + threadIdx.x) >> 4;
    if (g >= nRows) return;
    int lane = threadIdx.x & 15;
    int e = ptr2[2 * g + PHASE], end = ptr2[2 * g + PHASE + 1];
    float a0 = 0.0f, a1 = 0.0f;
    for (; e + 8 <= end; e += 8) {
        unsigned q0 = cv[e], q1 = cv[e + 1], q2 = cv[e + 2], q3 = cv[e + 3];
        unsigned q4 = cv[e + 4], q5 = cv[e + 5], q6 = cv[e + 6], q7 = cv[e + 7];
        unsigned v0 = yd[(size_t)(q0 & 0x1FFFFu) * 16 + lane];
        unsigned v1 = yd[(size_t)(q1 & 0x1FFFFu) * 16 + lane];
        unsigned v2 = yd[(size_t)(q2 & 0x1FFFFu) * 16 + lane];
        unsigned v3 = yd[(size_t)(q3 & 0x1FFFFu) * 16 + lane];
        unsigned v4 = yd[(size_t)(q4 & 0x1FFFFu) * 16 + lane];
        unsigned v5 = yd[(size_t)(q5 & 0x1FFFFu) * 16 + lane];
        unsigned v6 = yd[(size_t)(q6 & 0x1FFFFu) * 16 + lane];
        unsigned v7 = yd[(size_t)(q7 & 0x1FFFFu) * 16 + lane];
        float s0 = (float)(q0 >> 17), s1 = (float)(q1 >> 17);
        float s2 = (float)(q2 >> 17), s3 = (float)(q3 >> 17);
        float s4 = (float)(q4 >> 17), s5 = (float)(q5 >> 17);
        float s6 = (float)(q6 >> 17), s7 = (float)(q7 >> 17);
        a0 += s0 * lo_f(v0);  a1 += s0 * hi_f(v0);
        a0 += s1 * lo_f(v1);  a1 += s1 * hi_f(v1);
        a0 += s2 * lo_f(v2);  a1 += s2 * hi_f(v2);
        a0 += s3 * lo_f(v3);  a1 += s3 * hi_f(v3);
        a0 += s4 * lo_f(v4);  a1 += s4 * hi_f(v4);
        a0 += s5 * lo_f(v5);  a1 += s5 * hi_f(v5);
        a0 += s6 * lo_f(v6);  a1 += s6 * hi_f(v6);
        a0 += s7 * lo_f(v7);  a1 += s7 * hi_f(v7);
    }
    for (; e < end; ++e) {
        unsigned q = cv[e];
        unsigned v = yd[(size_t)(q & 0x1FFFFu) * 16 + lane];
        float s = (float)(q >> 17);
        a0 += s * lo_f(v);
        a1 += s * hi_f(v);
    }
    size_t idx = (size_t)g * 16 + lane;
    if (PHASE == 0) {
        part[idx] = make_float2(a0, a1);
    } else {
        float2 eb = emb2[idx];
        unsigned yv = yd[idx];
        float2 p = part[idx];
        float2 r;
        r.x = (eb.x + lo_f(yv) + (p.x + a0) * QINV) * (1.0f / 3.0f);
        r.y = (eb.y + hi_f(yv) + (p.y + a1) * QINV) * (1.0f / 3.0f);
        out2[idx] = r;
    }
}

// =================== atomic fallback ===================
__global__ __launch_bounds__(256) void spmm_atomic(
    const int* __restrict__ row, const int* __restrict__ col,
    const float* __restrict__ vals, const float* __restrict__ x,
    float* __restrict__ y, int nEdges, float scale) {
    long long t = (long long)blockIdx.x * blockDim.x + threadIdx.x;
    int e = (int)(t >> 5);
    if (e >= nEdges) return;
    int d = (int)(t & 31);
    float g = vals[e] * scale * x[(long long)col[e] * D + d];
    atomicAdd(&y[(long long)row[e] * D + d], g);
}
__global__ void combine_third(const float* __restrict__ emb,
                              const float* __restrict__ y1,
                              float* __restrict__ out, int n) {
    int i = blockIdx.x * blockDim.x + threadIdx.x;
    if (i < n) out[i] = (emb[i] + y1[i]) * (1.0f / 3.0f);
}

extern "C" void kernel_launch(void* const* d_in, const int* in_sizes, int n_in,
                              void* d_out, int out_size, void* d_ws, size_t ws_size,
                              hipStream_t stream) {
    const float* emb  = (const float*)d_in[0];
    const float* vals = (const float*)d_in[1];
    const int*   row  = (const int*)d_in[2];
    const int*   col  = (const int*)d_in[3];
    float* out = (float*)d_out;

    const int nElem  = in_sizes[0];          // N * 32
    const int nEdges = in_sizes[1];
    const int n      = nElem / D;            // 100001
    const int NB     = (n + RPB - 1) >> RPB_LOG;   // 391
    const int BLK = 256;
    const int nTiles = (nEdges + TILE - 1) / TILE; // 1563
    const int half   = n / 2;

    // workspace layout:
    //   misc | cv(uint2 8B*nE) | cv2(u32 4B*nE)
    //   tileCnt aliases cv2 (dead before csr_sort5 writes cv2)
    //   yd(4B/pair: nElem*2) | xd(nElem*2) | part(float2: nElem*4) alias cv
    size_t off_cnt    = 0;                                    // NB ints
    size_t off_bases  = off_cnt + (size_t)NB * 4;             // NB+1 ints
    size_t off_rowptr = off_bases + (size_t)(NB + 1) * 4;     // 2n+1 ints
    size_t off_cv     = (off_rowptr + (size_t)(2 * n + 1) * 4 + 63) & ~(size_t)63;
    size_t off_cv2    = off_cv + (size_t)nEdges * 8;
    size_t need       = off_cv2 + (size_t)nEdges * 4;

    bool aliasFit   = ((size_t)nElem * 8 <= (size_t)nEdges * 8);
    bool tileCntFit = ((size_t)nTiles * NB * 4 <= (size_t)nEdges * 4);
    bool ok = (NB <= MAXNB) && (n <= 131072) && (ws_size >= need) &&
              aliasFit && tileCntFit;

    if (!ok) {
        // fallback: atomic-scatter path (needs nElem floats)
        if (ws_size < (size_t)nElem * 4) return;
        float* y1 = (float*)d_ws;
        zero_f32<<<(nElem + BLK - 1) / BLK, BLK, 0, stream>>>(y1, nElem);
        long long threads = (long long)nEdges * 32;
        int blocks = (int)((threads + BLK - 1) / BLK);
        spmm_atomic<<<blocks, BLK, 0, stream>>>(row, col, vals, emb, y1, nEdges, 1.0f);
        combine_third<<<(nElem + BLK - 1) / BLK, BLK, 0, stream>>>(emb, y1, out, nElem);
        spmm_atomic<<<blocks, BLK, 0, stream>>>(row, col, vals, y1, out, nEdges, 1.0f / 3.0f);
        return;
    }

    char* ws = (char*)d_ws;
    int*            cnt     = (int*)(ws + off_cnt);
    int*            bases   = (int*)(ws + off_bases);
    int*            rowptr2 = (int*)(ws + off_rowptr);
    uint2*          cv      = (uint2*)(ws + off_cv);
    unsigned*       cv2     = (unsigned*)(ws + off_cv2);
    int*            tileCnt = (int*)(ws + off_cv2);           // alias
    unsigned*       yd      = (unsigned*)(ws + off_cv);       // y1 bf16 pairs
    unsigned short* embh    = (unsigned short*)(ws + off_cv + (size_t)nElem * 2);
    unsigned*       xd      = (unsigned*)embh;                // emb bf16 pairs
    float2*         part    = (float2*)(ws + off_cv + (size_t)nElem * 4);

    // 1) per-tile histograms
    tile_hist<<<nTiles, 256, 0, stream>>>(row, tileCnt, nEdges, NB);

    // 2) column scan (in-place) + bucket totals
    colscan<<<NB, 256, 0, stream>>>(tileCnt, cnt, nTiles, NB);

    // 3) bucket bases
    scan_buckets<<<1, 512, 0, stream>>>(cnt, bases, NB, nEdges);

    // 4) atomic-free partition into bucket regions
    partition_edges2<<<nTiles, PT2, 0, stream>>>(row, col, vals, bases,
                                                 tileCnt, cv, nEdges, NB);

    // 5) per bucket-half 512-key LDS-staged sort -> cv2 + rowptr2
    csr_sort5<<<2 * NB, 512, 0, stream>>>(bases, cv, cv2, rowptr2,
                                          n, nEdges, half);

    // 6) embh = bf16(emb)   (cv region is dead now)
    cast_bf16<<<(nElem + BLK - 1) / BLK, BLK, 0, stream>>>(emb, embh, nElem);

    // 7) layer 1: y1 = A*E, two L2-resident phases
    int rowBlocks = (n * 16 + BLK - 1) / BLK;
    spmm_l1<0><<<rowBlocks, BLK, 0, stream>>>(rowptr2, cv2, xd, part, yd, n);
    spmm_l1<1><<<rowBlocks, BLK, 0, stream>>>(rowptr2, cv2, xd, part, yd, n);

    // 8) layer 2 + combine: out = (E + y1 + A*y1)/3
    spmm_l2<0><<<rowBlocks, BLK, 0, stream>>>(rowptr2, cv2, yd,
                                              (const float2*)emb, part,
                                              (float2*)out, n);
    spmm_l2<1><<<rowBlocks, BLK, 0, stream>>>(rowptr2, cv2, yd,
                                              (const float2*)emb, part,
                                              (float2*)out, n);
}

// Round 18
// 239.295 us; speedup vs baseline: 1.5177x; 1.0302x over previous
//
#include <hip/hip_runtime.h>

// DyHuCoG: out = (E + A*E + A*(A*E)) / 3
// E: [N,32] f32, A: COO (vals f32, row i32, col i32), N=100001, nE=6400000.
//
// Pipeline (atomic-free (row,colhalf)-partition, 4B edges, col-split SpMM):
//   1) tile_hist: per-4096-edge tile histogram over 782 partitions
//      (partition = 256-row bucket x colhalf)
//   2) colscan:   in-place exclusive scan down each partition column
//   3) scan_buckets: partition bases
//   4) partition_edges2: LDS counting-sort per tile (NO global atomics),
//      coalesced run writes of uint2 {col|rowlow<<17, q15|part<<15}
//   5) csr_sort6: one block per partition, reads ONLY its own range (2x),
//      256-key (rowlow) LDS-staged sort -> cv2 (4B/edge) + seg[] bases
//   6) cast emb -> bf16 pairs
//   7) layer1 in 2 col phases (3.2MB gather set, L2-resident), 8 lanes/row,
//      uint2 gathers (4 bf16/lane): phase0 -> f32x4 partial, phase1 -> yd
//   8) layer2 same, phase1 fused with final combine (float4 I/O)

constexpr int D = 32;
constexpr int RPB_LOG = 8;               // rows per bucket = 256
constexpr int RPB = 1 << RPB_LOG;
constexpr int MAXNB = 800;               // max partitions (n <= 102400)
constexpr int TILE = 4096;               // edges per partition tile
constexpr int PT2 = 512;                 // partition threads
constexpr int CAP = 9728;                // LDS staging capacity (edges/part)
constexpr float QSCALE = 32768.0f;       // 15-bit val quantization
constexpr float QINV = 1.0f / 32768.0f;

__device__ __forceinline__ unsigned short f2bf(float f) {
    unsigned u = __float_as_uint(f);
    unsigned r = (u + 0x7FFFu + ((u >> 16) & 1u)) >> 16;   // RNE
    return (unsigned short)r;
}
__device__ __forceinline__ float lo_f(unsigned v) {       // bf16 pair low
    return __uint_as_float(v << 16);
}
__device__ __forceinline__ float hi_f(unsigned v) {       // bf16 pair high
    return __uint_as_float(v & 0xFFFF0000u);
}

__global__ void zero_f32(float* __restrict__ p, int n) {
    int i = blockIdx.x * blockDim.x + threadIdx.x;
    if (i < n) p[i] = 0.0f;
}
__global__ void cast_bf16(const float* __restrict__ in,
                          unsigned short* __restrict__ out, int n) {
    int i = blockIdx.x * blockDim.x + threadIdx.x;
    if (i < n) out[i] = f2bf(in[i]);
}

// ------- 1) per-tile partition histogram -> tileCnt[tile][NBp] -----------
__global__ __launch_bounds__(256) void tile_hist(
    const int* __restrict__ row, const int* __restrict__ col,
    int* __restrict__ tileCnt, int nE, int NBp, int half) {
    __shared__ int h[MAXNB];
    int tile = blockIdx.x;
    int base = tile * TILE;
    int n = min(TILE, nE - base);
    int t = threadIdx.x;
    for (int i = t; i < NBp; i += 256) h[i] = 0;
    __syncthreads();
    for (int i = t; i < n; i += 256) {
        int b = ((row[base + i] >> RPB_LOG) << 1) |
                ((col[base + i] >= half) ? 1 : 0);
        atomicAdd(&h[b], 1);
    }
    __syncthreads();
    for (int i = t; i < NBp; i += 256)
        tileCnt[(size_t)tile * NBp + i] = h[i];
}

// ------- 2) in-place exclusive column scan + partition totals ------------
__global__ __launch_bounds__(256) void colscan(
    int* __restrict__ tileCnt, int* __restrict__ cnt, int nTiles, int NBp) {
    __shared__ int s2[256];
    __shared__ int carryS;
    int b = blockIdx.x, t = threadIdx.x;
    if (t == 0) carryS = 0;
    __syncthreads();
    for (int c0 = 0; c0 < nTiles; c0 += 1024) {
        int v[4], idx[4];
        int sum = 0;
#pragma unroll
        for (int k = 0; k < 4; ++k) {
            idx[k] = c0 + t * 4 + k;
            v[k] = (idx[k] < nTiles) ? tileCnt[(size_t)idx[k] * NBp + b] : 0;
            sum += v[k];
        }
        s2[t] = sum;
        __syncthreads();
        for (int o = 1; o < 256; o <<= 1) {
            int x = (t >= o) ? s2[t - o] : 0;
            __syncthreads();
            s2[t] += x;
            __syncthreads();
        }
        int run = ((t == 0) ? 0 : s2[t - 1]) + carryS;
#pragma unroll
        for (int k = 0; k < 4; ++k) {
            if (idx[k] < nTiles) tileCnt[(size_t)idx[k] * NBp + b] = run;
            run += v[k];
        }
        __syncthreads();
        if (t == 0) carryS += s2[255];
        __syncthreads();
    }
    if (t == 0) cnt[b] = carryS;
}

// ---------------- 3) exclusive scan of partition counts (<= 1024) --------
__global__ __launch_bounds__(1024) void scan_buckets(
    const int* __restrict__ cnt, int* __restrict__ bases, int NBp, int nE) {
    __shared__ int s[1024];
    int t = threadIdx.x;
    s[t] = (t < NBp) ? cnt[t] : 0;
    __syncthreads();
    for (int o = 1; o < 1024; o <<= 1) {
        int v = (t >= o) ? s[t - o] : 0;
        __syncthreads();
        s[t] += v;
        __syncthreads();
    }
    if (t < NBp) bases[t] = (t == 0) ? 0 : s[t - 1];
    if (t == 0) bases[NBp] = nE;
}

// ------- 4) tiled partition, NO global atomics, coalesced writes ---------
__global__ __launch_bounds__(PT2) void partition_edges2(
    const int* __restrict__ row, const int* __restrict__ col,
    const float* __restrict__ vals, const int* __restrict__ bases,
    const int* __restrict__ tileCnt, uint2* __restrict__ cv,
    int nE, int NBp, int half) {
    __shared__ uint2 buf[TILE];            // 32 KB (also scan scratch)
    __shared__ int hist[MAXNB];            // 3.2 KB
    __shared__ int runoff[MAXNB];          // 3.2 KB
    int* s2 = (int*)buf;                   // scratch (buf unused pre-reorder)
    int t = threadIdx.x;
    int tile = blockIdx.x;
    int base = tile * TILE;
    int n = min(TILE, nE - base);
    if (n <= 0) return;
    for (int i = t; i < NBp; i += PT2) hist[i] = 0;
    __syncthreads();
    for (int i = t; i < n; i += PT2) {
        int b = ((row[base + i] >> RPB_LOG) << 1) |
                ((col[base + i] >= half) ? 1 : 0);
        atomicAdd(&hist[b], 1);
    }
    __syncthreads();
    // local exclusive scan of hist -> runoff (2 elems/thread covers 1024)
    {
        int b2 = t * 2;
        int a0 = (b2 + 0 < NBp) ? hist[b2 + 0] : 0;
        int a1 = (b2 + 1 < NBp) ? hist[b2 + 1] : 0;
        s2[t] = a0 + a1;
        __syncthreads();
        for (int o = 1; o < PT2; o <<= 1) {
            int v = (t >= o) ? s2[t - o] : 0;
            __syncthreads();
            s2[t] += v;
            __syncthreads();
        }
        int excl = (t == 0) ? 0 : s2[t - 1];
        if (b2 + 0 < NBp) runoff[b2 + 0] = excl;
        if (b2 + 1 < NBp) runoff[b2 + 1] = excl + a0;
    }
    __syncthreads();
    // hist[b] := global run base - runoff0[b]
    for (int i = t; i < NBp; i += PT2)
        hist[i] = bases[i] + tileCnt[(size_t)tile * NBp + i] - runoff[i];
    __syncthreads();
    // reorder into LDS partition-major; partition id packed in y bits 15..24
    for (int i = t; i < n; i += PT2) {
        int r = row[base + i];
        int c = col[base + i];
        int b = ((r >> RPB_LOG) << 1) | ((c >= half) ? 1 : 0);
        int slot = atomicAdd(&runoff[b], 1);
        float v = vals[base + i];
        int q = __float2int_rn(v * QSCALE);
        q = max(0, min(32767, q));
        uint2 p;
        p.x = (unsigned)c | ((unsigned)(r & (RPB - 1)) << 17);
        p.y = (unsigned)q | ((unsigned)b << 15);
        buf[slot] = p;
    }
    __syncthreads();
    // coalesced run writes: dest = hist[b] + slot (slot == i)
    for (int i = t; i < n; i += PT2) {
        uint2 v = buf[i];
        cv[hist[v.y >> 15] + i] = v;
    }
}

// ---- 5) per-partition 256-key LDS-staged sort -> cv2 + seg --------------
// Block p owns [bases[p], bases[p+1]); all its edges belong to it.
__global__ __launch_bounds__(512) void csr_sort6(
    const int* __restrict__ bases, const uint2* __restrict__ cv,
    unsigned* __restrict__ cv2, int* __restrict__ seg, int nSegTot, int nE) {
    __shared__ unsigned stage[CAP];        // 38 KB
    __shared__ int hist_s[RPB];            // 1 KB
    __shared__ int cur_s[RPB];             // 1 KB
    int t = threadIdx.x;
    int p = blockIdx.x;
    int s = bases[p], e = bases[p + 1];
    if (t < RPB) hist_s[t] = 0;
    __syncthreads();
    // pass 1: rowlow histogram of own range
    for (int i = s + t; i < e; i += 512)
        atomicAdd(&hist_s[cv[i].x >> 17], 1);
    __syncthreads();
    if (t < RPB) cur_s[t] = hist_s[t];
    __syncthreads();
    for (int o = 1; o < RPB; o <<= 1) {       // inclusive scan
        int v = 0;
        if (t < RPB && t >= o) v = cur_s[t - o];
        __syncthreads();
        if (t < RPB) cur_s[t] += v;
        __syncthreads();
    }
    int excl = 0;
    if (t < RPB) excl = (t == 0) ? 0 : cur_s[t - 1];
    __syncthreads();
    if (t < RPB) {
        seg[((size_t)p << 8) | t] = s + excl;
        cur_s[t] = excl;                      // local staging cursor
    }
    if (p == 0 && t == 0) seg[nSegTot] = nE;
    __syncthreads();
    int cnt = e - s;
    bool fits = (cnt <= CAP);
    // pass 2: re-read own range, stage (or direct-scatter on overflow)
    for (int i = s + t; i < e; i += 512) {
        uint2 pr = cv[i];
        int k = (int)(pr.x >> 17);
        int slot = atomicAdd(&cur_s[k], 1);
        unsigned packed = (pr.x & 0x1FFFFu) | ((pr.y & 0x7FFFu) << 17);
        if (fits) stage[slot] = packed;
        else      cv2[s + slot] = packed;
    }
    __syncthreads();
    // pass 3: coalesced write
    if (fits) {
        for (int j = t; j < cnt; j += 512)
            cv2[s + j] = stage[j];
    }
}

// ---- 7) layer-1 SpMM, 2 phases, 8 lanes/row, uint2 (4xbf16) gathers -----
template <int PHASE>
__global__ __launch_bounds__(256) void spmm_l1(
    const int* __restrict__ seg, const unsigned* __restrict__ cv,
    const uint2* __restrict__ xd2, float4* __restrict__ part4,
    uint2* __restrict__ yd2, int nRows) {
    int g = (blockIdx.x * 256 + threadIdx.x) >> 3;
    if (g >= nRows) return;
    int lane = threadIdx.x & 7;
    int si = ((g >> 8) << 9) | (PHASE << 8) | (g & 255);
    int e = seg[si], end = seg[si + 1];
    float a0 = 0.0f, a1 = 0.0f, a2 = 0.0f, a3 = 0.0f;
    for (; e + 4 <= end; e += 4) {
        unsigned q0 = cv[e], q1 = cv[e + 1], q2 = cv[e + 2], q3 = cv[e + 3];
        uint2 v0 = xd2[(size_t)(q0 & 0x1FFFFu) * 8 + lane];
        uint2 v1 = xd2[(size_t)(q1 & 0x1FFFFu) * 8 + lane];
        uint2 v2 = xd2[(size_t)(q2 & 0x1FFFFu) * 8 + lane];
        uint2 v3 = xd2[(size_t)(q3 & 0x1FFFFu) * 8 + lane];
        float s0 = (float)(q0 >> 17), s1 = (float)(q1 >> 17);
        float s2 = (float)(q2 >> 17), s3 = (float)(q3 >> 17);
        a0 += s0 * lo_f(v0.x);  a1 += s0 * hi_f(v0.x);
        a2 += s0 * lo_f(v0.y);  a3 += s0 * hi_f(v0.y);
        a0 += s1 * lo_f(v1.x);  a1 += s1 * hi_f(v1.x);
        a2 += s1 * lo_f(v1.y);  a3 += s1 * hi_f(v1.y);
        a0 += s2 * lo_f(v2.x);  a1 += s2 * hi_f(v2.x);
        a2 += s2 * lo_f(v2.y);  a3 += s2 * hi_f(v2.y);
        a0 += s3 * lo_f(v3.x);  a1 += s3 * hi_f(v3.x);
        a2 += s3 * lo_f(v3.y);  a3 += s3 * hi_f(v3.y);
    }
    for (; e < end; ++e) {
        unsigned q = cv[e];
        uint2 v = xd2[(size_t)(q & 0x1FFFFu) * 8 + lane];
        float s = (float)(q >> 17);
        a0 += s * lo_f(v.x);  a1 += s * hi_f(v.x);
        a2 += s * lo_f(v.y);  a3 += s * hi_f(v.y);
    }
    size_t idx = (size_t)g * 8 + lane;
    if (PHASE == 0) {
        part4[idx] = make_float4(a0, a1, a2, a3);
    } else {
        float4 p = part4[idx];
        uint2 o;
        o.x = (unsigned)f2bf((p.x + a0) * QINV) |
              ((unsigned)f2bf((p.y + a1) * QINV) << 16);
        o.y = (unsigned)f2bf((p.z + a2) * QINV) |
              ((unsigned)f2bf((p.w + a3) * QINV) << 16);
        yd2[idx] = o;
    }
}

// ---- 8) layer-2 SpMM, 2 phases, phase 1 fused with combine --------------
template <int PHASE>
__global__ __launch_bounds__(256) void spmm_l2(
    const int* __restrict__ seg, const unsigned* __restrict__ cv,
    const uint2* __restrict__ yd2, const float4* __restrict__ emb4,
    float4* __restrict__ part4, float4* __restrict__ out4, int nRows) {
    int g = (blockIdx.x * 256 + threadIdx.x) >> 3;
    if (g >= nRows) return;
    int lane = threadIdx.x & 7;
    int si = ((g >> 8) << 9) | (PHASE << 8) | (g & 255);
    int e = seg[si], end = seg[si + 1];
    float a0 = 0.0f, a1 = 0.0f, a2 = 0.0f, a3 = 0.0f;
    for (; e + 4 <= end; e += 4) {
        unsigned q0 = cv[e], q1 = cv[e + 1], q2 = cv[e + 2], q3 = cv[e + 3];
        uint2 v0 = yd2[(size_t)(q0 & 0x1FFFFu) * 8 + lane];
        uint2 v1 = yd2[(size_t)(q1 & 0x1FFFFu) * 8 + lane];
        uint2 v2 = yd2[(size_t)(q2 & 0x1FFFFu) * 8 + lane];
        uint2 v3 = yd2[(size_t)(q3 & 0x1FFFFu) * 8 + lane];
        float s0 = (float)(q0 >> 17), s1 = (float)(q1 >> 17);
        float s2 = (float)(q2 >> 17), s3 = (float)(q3 >> 17);
        a0 += s0 * lo_f(v0.x);  a1 += s0 * hi_f(v0.x);
        a2 += s0 * lo_f(v0.y);  a3 += s0 * hi_f(v0.y);
        a0 += s1 * lo_f(v1.x);  a1 += s1 * hi_f(v1.x);
        a2 += s1 * lo_f(v1.y);  a3 += s1 * hi_f(v1.y);
        a0 += s2 * lo_f(v2.x);  a1 += s2 * hi_f(v2.x);
        a2 += s2 * lo_f(v2.y);  a3 += s2 * hi_f(v2.y);
        a0 += s3 * lo_f(v3.x);  a1 += s3 * hi_f(v3.x);
        a2 += s3 * lo_f(v3.y);  a3 += s3 * hi_f(v3.y);
    }
    for (; e < end; ++e) {
        unsigned q = cv[e];
        uint2 v = yd2[(size_t)(q & 0x1FFFFu) * 8 + lane];
        float s = (float)(q >> 17);
        a0 += s * lo_f(v.x);  a1 += s * hi_f(v.x);
        a2 += s * lo_f(v.y);  a3 += s * hi_f(v.y);
    }
    size_t idx = (size_t)g * 8 + lane;
    if (PHASE == 0) {
        part4[idx] = make_float4(a0, a1, a2, a3);
    } else {
        float4 eb = emb4[idx];
        uint2 yv = yd2[idx];
        float4 p = part4[idx];
        float4 r;
        r.x = (eb.x + lo_f(yv.x) + (p.x + a0) * QINV) * (1.0f / 3.0f);
        r.y = (eb.y + hi_f(yv.x) + (p.y + a1) * QINV) * (1.0f / 3.0f);
        r.z = (eb.z + lo_f(yv.y) + (p.z + a2) * QINV) * (1.0f / 3.0f);
        r.w = (eb.w + hi_f(yv.y) + (p.w + a3) * QINV) * (1.0f / 3.0f);
        out4[idx] = r;
    }
}

// =================== atomic fallback ===================
__global__ __launch_bounds__(256) void spmm_atomic(
    const int* __restrict__ row, const int* __restrict__ col,
    const float* __restrict__ vals, const float* __restrict__ x,
    float* __restrict__ y, int nEdges, float scale) {
    long long t = (long long)blockIdx.x * blockDim.x + threadIdx.x;
    int e = (int)(t >> 5);
    if (e >= nEdges) return;
    int d = (int)(t & 31);
    float g = vals[e] * scale * x[(long long)col[e] * D + d];
    atomicAdd(&y[(long long)row[e] * D + d], g);
}
__global__ void combine_third(const float* __restrict__ emb,
                              const float* __restrict__ y1,
                              float* __restrict__ out, int n) {
    int i = blockIdx.x * blockDim.x + threadIdx.x;
    if (i < n) out[i] = (emb[i] + y1[i]) * (1.0f / 3.0f);
}

extern "C" void kernel_launch(void* const* d_in, const int* in_sizes, int n_in,
                              void* d_out, int out_size, void* d_ws, size_t ws_size,
                              hipStream_t stream) {
    const float* emb  = (const float*)d_in[0];
    const float* vals = (const float*)d_in[1];
    const int*   row  = (const int*)d_in[2];
    const int*   col  = (const int*)d_in[3];
    float* out = (float*)d_out;

    const int nElem  = in_sizes[0];          // N * 32
    const int nEdges = in_sizes[1];
    const int n      = nElem / D;            // 100001
    const int NBb    = (n + RPB - 1) >> RPB_LOG;   // 256-row buckets (391)
    const int NBp    = NBb * 2;                    // partitions (782)
    const int BLK = 256;
    const int nTiles = (nEdges + TILE - 1) / TILE; // 1563
    const int half   = n / 2;
    const int nSegTot = NBp * 256;                 // = NBb*512

    // workspace layout:
    //   cnt(NBp) | bases(NBp+1) | seg(nSegTot+1) | cv(8B*nE) | cv2(4B*nE)
    //   tileCnt aliases cv2 (dead before csr_sort6 writes cv2)
    //   yd2(2B/elem) | xd2(2B/elem) | part4(4B/elem) alias cv
    size_t off_cnt   = 0;                                     // NBp ints
    size_t off_bases = off_cnt + (size_t)NBp * 4;             // NBp+1 ints
    size_t off_seg   = off_bases + (size_t)(NBp + 1) * 4;     // nSegTot+1
    size_t off_cv    = (off_seg + (size_t)(nSegTot + 1) * 4 + 63) & ~(size_t)63;
    size_t off_cv2   = off_cv + (size_t)nEdges * 8;
    size_t need      = off_cv2 + (size_t)nEdges * 4;

    bool aliasFit   = ((size_t)nElem * 8 <= (size_t)nEdges * 8);
    bool tileCntFit = ((size_t)nTiles * NBp <= (size_t)nEdges);
    bool ok = (NBp <= MAXNB) && (n <= 102400) && (ws_size >= need) &&
              aliasFit && tileCntFit;

    if (!ok) {
        // fallback: atomic-scatter path (needs nElem floats)
        if (ws_size < (size_t)nElem * 4) return;
        float* y1 = (float*)d_ws;
        zero_f32<<<(nElem + BLK - 1) / BLK, BLK, 0, stream>>>(y1, nElem);
        long long threads = (long long)nEdges * 32;
        int blocks = (int)((threads + BLK - 1) / BLK);
        spmm_atomic<<<blocks, BLK, 0, stream>>>(row, col, vals, emb, y1, nEdges, 1.0f);
        combine_third<<<(nElem + BLK - 1) / BLK, BLK, 0, stream>>>(emb, y1, out, nElem);
        spmm_atomic<<<blocks, BLK, 0, stream>>>(row, col, vals, y1, out, nEdges, 1.0f / 3.0f);
        return;
    }

    char* ws = (char*)d_ws;
    int*            cnt     = (int*)(ws + off_cnt);
    int*            bases   = (int*)(ws + off_bases);
    int*            seg     = (int*)(ws + off_seg);
    uint2*          cv      = (uint2*)(ws + off_cv);
    unsigned*       cv2     = (unsigned*)(ws + off_cv2);
    int*            tileCnt = (int*)(ws + off_cv2);           // alias
    uint2*          yd2     = (uint2*)(ws + off_cv);          // alias (cv dead)
    unsigned short* embh    = (unsigned short*)(ws + off_cv + (size_t)nElem * 2);
    uint2*          xd2     = (uint2*)embh;
    float4*         part4   = (float4*)(ws + off_cv + (size_t)nElem * 4);

    // 1) per-tile partition histograms
    tile_hist<<<nTiles, 256, 0, stream>>>(row, col, tileCnt, nEdges, NBp, half);

    // 2) column scan (in-place) + partition totals
    colscan<<<NBp, 256, 0, stream>>>(tileCnt, cnt, nTiles, NBp);

    // 3) partition bases
    scan_buckets<<<1, 1024, 0, stream>>>(cnt, bases, NBp, nEdges);

    // 4) atomic-free partition into (bucket, colhalf) regions
    partition_edges2<<<nTiles, PT2, 0, stream>>>(row, col, vals, bases,
                                                 tileCnt, cv, nEdges, NBp, half);

    // 5) per-partition 256-key LDS-staged sort -> cv2 + seg
    csr_sort6<<<NBp, 512, 0, stream>>>(bases, cv, cv2, seg, nSegTot, nEdges);

    // 6) embh = bf16(emb)   (cv region is dead now)
    cast_bf16<<<(nElem + BLK - 1) / BLK, BLK, 0, stream>>>(emb, embh, nElem);

    // 7) layer 1: y1 = A*E, two L2-resident phases (8 lanes/row)
    int rowBlocks = (n * 8 + BLK - 1) / BLK;
    spmm_l1<0><<<rowBlocks, BLK, 0, stream>>>(seg, cv2, xd2, part4, yd2, n);
    spmm_l1<1><<<rowBlocks, BLK, 0, stream>>>(seg, cv2, xd2, part4, yd2, n);

    // 8) layer 2 + combine: out = (E + y1 + A*y1)/3
    spmm_l2<0><<<rowBlocks, BLK, 0, stream>>>(seg, cv2, yd2,
                                              (const float4*)emb, part4,
                                              (float4*)out, n);
    spmm_l2<1><<<rowBlocks, BLK, 0, stream>>>(seg, cv2, yd2,
                                              (const float4*)emb, part4,
                                              (float4*)out, n);
}

// Round 19
// 228.947 us; speedup vs baseline: 1.5863x; 1.0452x over previous
//
#include <hip/hip_runtime.h>

// DyHuCoG: out = (E + A*E + A*(A*E)) / 3
// E: [N,32] f32, A: COO (vals f32, row i32, col i32), N=100001, nE=6400000.
//
// Pipeline (atomic-free (row,colhalf)-partition, 4B edges, col-split SpMM):
//   1) tile_hist: per-4096-edge tile histogram over 782 partitions
//   2) colscan:   OUT-OF-PLACE column scan: tileCnt (counts, kept) ->
//      colbase (per-(tile,part) run bases) + cnt (partition totals)
//   3) scan_buckets: partition bases
//   4) partition_edges3: NO histogram pass (runoff from tileCnt row),
//      LDS reorder + coalesced run writes of uint2 {col|rowlow<<17, q15|part<<15}
//   5) csr_sort6: one block per partition, reads ONLY its own range (2x),
//      256-key (rowlow) LDS-staged sort -> cv2 (4B/edge) + seg[] bases
//   6) cast emb -> bf16 pairs
//   7) layer1 in 2 col phases (3.2MB gather set, L2-resident), 8 lanes/row,
//      uint2 gathers: phase0 -> f32x4 partial, phase1 -> yd
//   8) layer2 same, phase1 fused with final combine (float4 I/O)

constexpr int D = 32;
constexpr int RPB_LOG = 8;               // rows per bucket = 256
constexpr int RPB = 1 << RPB_LOG;
constexpr int MAXNB = 800;               // max partitions (n <= 102400)
constexpr int TILE = 4096;               // edges per partition tile
constexpr int PT2 = 512;                 // partition threads
constexpr int CAP = 9728;                // LDS staging capacity (edges/part)
constexpr float QSCALE = 32768.0f;       // 15-bit val quantization
constexpr float QINV = 1.0f / 32768.0f;

__device__ __forceinline__ unsigned short f2bf(float f) {
    unsigned u = __float_as_uint(f);
    unsigned r = (u + 0x7FFFu + ((u >> 16) & 1u)) >> 16;   // RNE
    return (unsigned short)r;
}
__device__ __forceinline__ float lo_f(unsigned v) {       // bf16 pair low
    return __uint_as_float(v << 16);
}
__device__ __forceinline__ float hi_f(unsigned v) {       // bf16 pair high
    return __uint_as_float(v & 0xFFFF0000u);
}

__global__ void zero_f32(float* __restrict__ p, int n) {
    int i = blockIdx.x * blockDim.x + threadIdx.x;
    if (i < n) p[i] = 0.0f;
}
__global__ void cast_bf16(const float* __restrict__ in,
                          unsigned short* __restrict__ out, int n) {
    int i = blockIdx.x * blockDim.x + threadIdx.x;
    if (i < n) out[i] = f2bf(in[i]);
}

// ------- 1) per-tile partition histogram -> tileCnt[tile][NBp] -----------
__global__ __launch_bounds__(256) void tile_hist(
    const int* __restrict__ row, const int* __restrict__ col,
    int* __restrict__ tileCnt, int nE, int NBp, int half) {
    __shared__ int h[MAXNB];
    int tile = blockIdx.x;
    int base = tile * TILE;
    int n = min(TILE, nE - base);
    int t = threadIdx.x;
    for (int i = t; i < NBp; i += 256) h[i] = 0;
    __syncthreads();
    for (int i = t; i < n; i += 256) {
        int b = ((row[base + i] >> RPB_LOG) << 1) |
                ((col[base + i] >= half) ? 1 : 0);
        atomicAdd(&h[b], 1);
    }
    __syncthreads();
    for (int i = t; i < NBp; i += 256)
        tileCnt[(size_t)tile * NBp + i] = h[i];
}

// ------- 2) out-of-place column scan: tileCnt -> colbase + totals --------
__global__ __launch_bounds__(256) void colscan(
    const int* __restrict__ tileCnt, int* __restrict__ colbase,
    int* __restrict__ cnt, int nTiles, int NBp) {
    __shared__ int s2[256];
    __shared__ int carryS;
    int b = blockIdx.x, t = threadIdx.x;
    if (t == 0) carryS = 0;
    __syncthreads();
    for (int c0 = 0; c0 < nTiles; c0 += 1024) {
        int v[4], idx[4];
        int sum = 0;
#pragma unroll
        for (int k = 0; k < 4; ++k) {
            idx[k] = c0 + t * 4 + k;
            v[k] = (idx[k] < nTiles) ? tileCnt[(size_t)idx[k] * NBp + b] : 0;
            sum += v[k];
        }
        s2[t] = sum;
        __syncthreads();
        for (int o = 1; o < 256; o <<= 1) {
            int x = (t >= o) ? s2[t - o] : 0;
            __syncthreads();
            s2[t] += x;
            __syncthreads();
        }
        int run = ((t == 0) ? 0 : s2[t - 1]) + carryS;
#pragma unroll
        for (int k = 0; k < 4; ++k) {
            if (idx[k] < nTiles) colbase[(size_t)idx[k] * NBp + b] = run;
            run += v[k];
        }
        __syncthreads();
        if (t == 0) carryS += s2[255];
        __syncthreads();
    }
    if (t == 0) cnt[b] = carryS;
}

// ---------------- 3) exclusive scan of partition counts (<= 1024) --------
__global__ __launch_bounds__(1024) void scan_buckets(
    const int* __restrict__ cnt, int* __restrict__ bases, int NBp, int nE) {
    __shared__ int s[1024];
    int t = threadIdx.x;
    s[t] = (t < NBp) ? cnt[t] : 0;
    __syncthreads();
    for (int o = 1; o < 1024; o <<= 1) {
        int v = (t >= o) ? s[t - o] : 0;
        __syncthreads();
        s[t] += v;
        __syncthreads();
    }
    if (t < NBp) bases[t] = (t == 0) ? 0 : s[t - 1];
    if (t == 0) bases[NBp] = nE;
}

// ------- 4) tiled partition, NO hist pass, coalesced writes --------------
__global__ __launch_bounds__(PT2) void partition_edges3(
    const int* __restrict__ row, const int* __restrict__ col,
    const float* __restrict__ vals, const int* __restrict__ bases,
    const int* __restrict__ tileCnt, const int* __restrict__ colbase,
    uint2* __restrict__ cv, int nE, int NBp, int half) {
    __shared__ uint2 buf[TILE];            // 32 KB (also scan scratch)
    __shared__ int hist[MAXNB];            // 3.2 KB (runbase - runoff0)
    __shared__ int runoff[MAXNB];          // 3.2 KB (running local cursor)
    int* s2 = (int*)buf;                   // scratch (buf unused pre-reorder)
    int t = threadIdx.x;
    int tile = blockIdx.x;
    int base = tile * TILE;
    int n = min(TILE, nE - base);
    if (n <= 0) return;
    // local exclusive scan of tileCnt[tile][*] -> runoff (2 elems/thread)
    int b2 = t * 2;
    int a0 = (b2 + 0 < NBp) ? tileCnt[(size_t)tile * NBp + b2 + 0] : 0;
    int a1 = (b2 + 1 < NBp) ? tileCnt[(size_t)tile * NBp + b2 + 1] : 0;
    s2[t] = a0 + a1;
    __syncthreads();
    for (int o = 1; o < PT2; o <<= 1) {
        int v = (t >= o) ? s2[t - o] : 0;
        __syncthreads();
        s2[t] += v;
        __syncthreads();
    }
    {
        int excl = (t == 0) ? 0 : s2[t - 1];
        if (b2 + 0 < NBp) runoff[b2 + 0] = excl;
        if (b2 + 1 < NBp) runoff[b2 + 1] = excl + a0;
    }
    __syncthreads();
    // hist[b] := global run base - runoff0[b]
    for (int i = t; i < NBp; i += PT2)
        hist[i] = bases[i] + colbase[(size_t)tile * NBp + i] - runoff[i];
    __syncthreads();
    // reorder into LDS partition-major; partition id packed in y bits 15..24
    for (int i = t; i < n; i += PT2) {
        int r = row[base + i];
        int c = col[base + i];
        int b = ((r >> RPB_LOG) << 1) | ((c >= half) ? 1 : 0);
        int slot = atomicAdd(&runoff[b], 1);
        float v = vals[base + i];
        int q = __float2int_rn(v * QSCALE);
        q = max(0, min(32767, q));
        uint2 p;
        p.x = (unsigned)c | ((unsigned)(r & (RPB - 1)) << 17);
        p.y = (unsigned)q | ((unsigned)b << 15);
        buf[slot] = p;
    }
    __syncthreads();
    // coalesced run writes: dest = hist[b] + slot (slot == i)
    for (int i = t; i < n; i += PT2) {
        uint2 v = buf[i];
        cv[hist[v.y >> 15] + i] = v;
    }
}

// ---- 5) per-partition 256-key LDS-staged sort -> cv2 + seg --------------
__global__ __launch_bounds__(512) void csr_sort6(
    const int* __restrict__ bases, const uint2* __restrict__ cv,
    unsigned* __restrict__ cv2, int* __restrict__ seg, int nSegTot, int nE) {
    __shared__ unsigned stage[CAP];        // 38 KB
    __shared__ int hist_s[RPB];            // 1 KB
    __shared__ int cur_s[RPB];             // 1 KB
    int t = threadIdx.x;
    int p = blockIdx.x;
    int s = bases[p], e = bases[p + 1];
    if (t < RPB) hist_s[t] = 0;
    __syncthreads();
    // pass 1: rowlow histogram of own range
    for (int i = s + t; i < e; i += 512)
        atomicAdd(&hist_s[cv[i].x >> 17], 1);
    __syncthreads();
    if (t < RPB) cur_s[t] = hist_s[t];
    __syncthreads();
    for (int o = 1; o < RPB; o <<= 1) {       // inclusive scan
        int v = 0;
        if (t < RPB && t >= o) v = cur_s[t - o];
        __syncthreads();
        if (t < RPB) cur_s[t] += v;
        __syncthreads();
    }
    int excl = 0;
    if (t < RPB) excl = (t == 0) ? 0 : cur_s[t - 1];
    __syncthreads();
    if (t < RPB) {
        seg[((size_t)p << 8) | t] = s + excl;
        cur_s[t] = excl;                      // local staging cursor
    }
    if (p == 0 && t == 0) seg[nSegTot] = nE;
    __syncthreads();
    int cnt = e - s;
    bool fits = (cnt <= CAP);
    // pass 2: re-read own range, stage (or direct-scatter on overflow)
    for (int i = s + t; i < e; i += 512) {
        uint2 pr = cv[i];
        int k = (int)(pr.x >> 17);
        int slot = atomicAdd(&cur_s[k], 1);
        unsigned packed = (pr.x & 0x1FFFFu) | ((pr.y & 0x7FFFu) << 17);
        if (fits) stage[slot] = packed;
        else      cv2[s + slot] = packed;
    }
    __syncthreads();
    // pass 3: coalesced write
    if (fits) {
        for (int j = t; j < cnt; j += 512)
            cv2[s + j] = stage[j];
    }
}

// ---- 7) layer-1 SpMM, 2 phases, 8 lanes/row, uint2 (4xbf16) gathers -----
template <int PHASE>
__global__ __launch_bounds__(256) void spmm_l1(
    const int* __restrict__ seg, const unsigned* __restrict__ cv,
    const uint2* __restrict__ xd2, float4* __restrict__ part4,
    uint2* __restrict__ yd2, int nRows) {
    int g = (blockIdx.x * 256 + threadIdx.x) >> 3;
    if (g >= nRows) return;
    int lane = threadIdx.x & 7;
    int si = ((g >> 8) << 9) | (PHASE << 8) | (g & 255);
    int e = seg[si], end = seg[si + 1];
    float a0 = 0.0f, a1 = 0.0f, a2 = 0.0f, a3 = 0.0f;
    for (; e + 4 <= end; e += 4) {
        unsigned q0 = cv[e], q1 = cv[e + 1], q2 = cv[e + 2], q3 = cv[e + 3];
        uint2 v0 = xd2[(size_t)(q0 & 0x1FFFFu) * 8 + lane];
        uint2 v1 = xd2[(size_t)(q1 & 0x1FFFFu) * 8 + lane];
        uint2 v2 = xd2[(size_t)(q2 & 0x1FFFFu) * 8 + lane];
        uint2 v3 = xd2[(size_t)(q3 & 0x1FFFFu) * 8 + lane];
        float s0 = (float)(q0 >> 17), s1 = (float)(q1 >> 17);
        float s2 = (float)(q2 >> 17), s3 = (float)(q3 >> 17);
        a0 += s0 * lo_f(v0.x);  a1 += s0 * hi_f(v0.x);
        a2 += s0 * lo_f(v0.y);  a3 += s0 * hi_f(v0.y);
        a0 += s1 * lo_f(v1.x);  a1 += s1 * hi_f(v1.x);
        a2 += s1 * lo_f(v1.y);  a3 += s1 * hi_f(v1.y);
        a0 += s2 * lo_f(v2.x);  a1 += s2 * hi_f(v2.x);
        a2 += s2 * lo_f(v2.y);  a3 += s2 * hi_f(v2.y);
        a0 += s3 * lo_f(v3.x);  a1 += s3 * hi_f(v3.x);
        a2 += s3 * lo_f(v3.y);  a3 += s3 * hi_f(v3.y);
    }
    for (; e < end; ++e) {
        unsigned q = cv[e];
        uint2 v = xd2[(size_t)(q & 0x1FFFFu) * 8 + lane];
        float s = (float)(q >> 17);
        a0 += s * lo_f(v.x);  a1 += s * hi_f(v.x);
        a2 += s * lo_f(v.y);  a3 += s * hi_f(v.y);
    }
    size_t idx = (size_t)g * 8 + lane;
    if (PHASE == 0) {
        part4[idx] = make_float4(a0, a1, a2, a3);
    } else {
        float4 p = part4[idx];
        uint2 o;
        o.x = (unsigned)f2bf((p.x + a0) * QINV) |
              ((unsigned)f2bf((p.y + a1) * QINV) << 16);
        o.y = (unsigned)f2bf((p.z + a2) * QINV) |
              ((unsigned)f2bf((p.w + a3) * QINV) << 16);
        yd2[idx] = o;
    }
}

// ---- 8) layer-2 SpMM, 2 phases, phase 1 fused with combine --------------
template <int PHASE>
__global__ __launch_bounds__(256) void spmm_l2(
    const int* __restrict__ seg, const unsigned* __restrict__ cv,
    const uint2* __restrict__ yd2, const float4* __restrict__ emb4,
    float4* __restrict__ part4, float4* __restrict__ out4, int nRows) {
    int g = (blockIdx.x * 256 + threadIdx.x) >> 3;
    if (g >= nRows) return;
    int lane = threadIdx.x & 7;
    int si = ((g >> 8) << 9) | (PHASE << 8) | (g & 255);
    int e = seg[si], end = seg[si + 1];
    float a0 = 0.0f, a1 = 0.0f, a2 = 0.0f, a3 = 0.0f;
    for (; e + 4 <= end; e += 4) {
        unsigned q0 = cv[e], q1 = cv[e + 1], q2 = cv[e + 2], q3 = cv[e + 3];
        uint2 v0 = yd2[(size_t)(q0 & 0x1FFFFu) * 8 + lane];
        uint2 v1 = yd2[(size_t)(q1 & 0x1FFFFu) * 8 + lane];
        uint2 v2 = yd2[(size_t)(q2 & 0x1FFFFu) * 8 + lane];
        uint2 v3 = yd2[(size_t)(q3 & 0x1FFFFu) * 8 + lane];
        float s0 = (float)(q0 >> 17), s1 = (float)(q1 >> 17);
        float s2 = (float)(q2 >> 17), s3 = (float)(q3 >> 17);
        a0 += s0 * lo_f(v0.x);  a1 += s0 * hi_f(v0.x);
        a2 += s0 * lo_f(v0.y);  a3 += s0 * hi_f(v0.y);
        a0 += s1 * lo_f(v1.x);  a1 += s1 * hi_f(v1.x);
        a2 += s1 * lo_f(v1.y);  a3 += s1 * hi_f(v1.y);
        a0 += s2 * lo_f(v2.x);  a1 += s2 * hi_f(v2.x);
        a2 += s2 * lo_f(v2.y);  a3 += s2 * hi_f(v2.y);
        a0 += s3 * lo_f(v3.x);  a1 += s3 * hi_f(v3.x);
        a2 += s3 * lo_f(v3.y);  a3 += s3 * hi_f(v3.y);
    }
    for (; e < end; ++e) {
        unsigned q = cv[e];
        uint2 v = yd2[(size_t)(q & 0x1FFFFu) * 8 + lane];
        float s = (float)(q >> 17);
        a0 += s * lo_f(v.x);  a1 += s * hi_f(v.x);
        a2 += s * lo_f(v.y);  a3 += s * hi_f(v.y);
    }
    size_t idx = (size_t)g * 8 + lane;
    if (PHASE == 0) {
        part4[idx] = make_float4(a0, a1, a2, a3);
    } else {
        float4 eb = emb4[idx];
        uint2 yv = yd2[idx];
        float4 p = part4[idx];
        float4 r;
        r.x = (eb.x + lo_f(yv.x) + (p.x + a0) * QINV) * (1.0f / 3.0f);
        r.y = (eb.y + hi_f(yv.x) + (p.y + a1) * QINV) * (1.0f / 3.0f);
        r.z = (eb.z + lo_f(yv.y) + (p.z + a2) * QINV) * (1.0f / 3.0f);
        r.w = (eb.w + hi_f(yv.y) + (p.w + a3) * QINV) * (1.0f / 3.0f);
        out4[idx] = r;
    }
}

// =================== atomic fallback ===================
__global__ __launch_bounds__(256) void spmm_atomic(
    const int* __restrict__ row, const int* __restrict__ col,
    const float* __restrict__ vals, const float* __restrict__ x,
    float* __restrict__ y, int nEdges, float scale) {
    long long t = (long long)blockIdx.x * blockDim.x + threadIdx.x;
    int e = (int)(t >> 5);
    if (e >= nEdges) return;
    int d = (int)(t & 31);
    float g = vals[e] * scale * x[(long long)col[e] * D + d];
    atomicAdd(&y[(long long)row[e] * D + d], g);
}
__global__ void combine_third(const float* __restrict__ emb,
                              const float* __restrict__ y1,
                              float* __restrict__ out, int n) {
    int i = blockIdx.x * blockDim.x + threadIdx.x;
    if (i < n) out[i] = (emb[i] + y1[i]) * (1.0f / 3.0f);
}

extern "C" void kernel_launch(void* const* d_in, const int* in_sizes, int n_in,
                              void* d_out, int out_size, void* d_ws, size_t ws_size,
                              hipStream_t stream) {
    const float* emb  = (const float*)d_in[0];
    const float* vals = (const float*)d_in[1];
    const int*   row  = (const int*)d_in[2];
    const int*   col  = (const int*)d_in[3];
    float* out = (float*)d_out;

    const int nElem  = in_sizes[0];          // N * 32
    const int nEdges = in_sizes[1];
    const int n      = nElem / D;            // 100001
    const int NBb    = (n + RPB - 1) >> RPB_LOG;   // 256-row buckets (391)
    const int NBp    = NBb * 2;                    // partitions (782)
    const int BLK = 256;
    const int nTiles = (nEdges + TILE - 1) / TILE; // 1563
    const int half   = n / 2;
    const int nSegTot = NBp * 256;                 // = NBb*512

    // workspace layout:
    //   cnt(NBp) | bases(NBp+1) | seg(nSegTot+1) | cv(8B*nE) | cv2(4B*nE)
    //   tileCnt + colbase alias cv2 (dead before csr_sort6 writes cv2)
    //   yd2 | xd2 | part4 alias cv (dead after csr_sort6)
    size_t off_cnt   = 0;                                     // NBp ints
    size_t off_bases = off_cnt + (size_t)NBp * 4;             // NBp+1 ints
    size_t off_seg   = off_bases + (size_t)(NBp + 1) * 4;     // nSegTot+1
    size_t off_cv    = (off_seg + (size_t)(nSegTot + 1) * 4 + 63) & ~(size_t)63;
    size_t off_cv2   = off_cv + (size_t)nEdges * 8;
    size_t need      = off_cv2 + (size_t)nEdges * 4;

    size_t sz_tc = (size_t)nTiles * NBp * 4;
    bool aliasFit   = ((size_t)nElem * 8 <= (size_t)nEdges * 8);
    bool tileCntFit = (2 * sz_tc <= (size_t)nEdges * 4);
    bool ok = (NBp <= MAXNB) && (n <= 102400) && (ws_size >= need) &&
              aliasFit && tileCntFit;

    if (!ok) {
        // fallback: atomic-scatter path (needs nElem floats)
        if (ws_size < (size_t)nElem * 4) return;
        float* y1 = (float*)d_ws;
        zero_f32<<<(nElem + BLK - 1) / BLK, BLK, 0, stream>>>(y1, nElem);
        long long threads = (long long)nEdges * 32;
        int blocks = (int)((threads + BLK - 1) / BLK);
        spmm_atomic<<<blocks, BLK, 0, stream>>>(row, col, vals, emb, y1, nEdges, 1.0f);
        combine_third<<<(nElem + BLK - 1) / BLK, BLK, 0, stream>>>(emb, y1, out, nElem);
        spmm_atomic<<<blocks, BLK, 0, stream>>>(row, col, vals, y1, out, nEdges, 1.0f / 3.0f);
        return;
    }

    char* ws = (char*)d_ws;
    int*            cnt     = (int*)(ws + off_cnt);
    int*            bases   = (int*)(ws + off_bases);
    int*            seg     = (int*)(ws + off_seg);
    uint2*          cv      = (uint2*)(ws + off_cv);
    unsigned*       cv2     = (unsigned*)(ws + off_cv2);
    int*            tileCnt = (int*)(ws + off_cv2);           // alias
    int*            colbase = (int*)(ws + off_cv2 + sz_tc);   // alias
    uint2*          yd2     = (uint2*)(ws + off_cv);          // alias (cv dead)
    unsigned short* embh    = (unsigned short*)(ws + off_cv + (size_t)nElem * 2);
    uint2*          xd2     = (uint2*)embh;
    float4*         part4   = (float4*)(ws + off_cv + (size_t)nElem * 4);

    // 1) per-tile partition histograms (counts, kept)
    tile_hist<<<nTiles, 256, 0, stream>>>(row, col, tileCnt, nEdges, NBp, half);

    // 2) out-of-place column scan -> colbase + partition totals
    colscan<<<NBp, 256, 0, stream>>>(tileCnt, colbase, cnt, nTiles, NBp);

    // 3) partition bases
    scan_buckets<<<1, 1024, 0, stream>>>(cnt, bases, NBp, nEdges);

    // 4) atomic-free partition (no hist pass; runoff from tileCnt row)
    partition_edges3<<<nTiles, PT2, 0, stream>>>(row, col, vals, bases,
                                                 tileCnt, colbase, cv,
                                                 nEdges, NBp, half);

    // 5) per-partition 256-key LDS-staged sort -> cv2 + seg
    csr_sort6<<<NBp, 512, 0, stream>>>(bases, cv, cv2, seg, nSegTot, nEdges);

    // 6) embh = bf16(emb)   (cv region is dead now)
    cast_bf16<<<(nElem + BLK - 1) / BLK, BLK, 0, stream>>>(emb, embh, nElem);

    // 7) layer 1: y1 = A*E, two L2-resident phases (8 lanes/row)
    int rowBlocks = (n * 8 + BLK - 1) / BLK;
    spmm_l1<0><<<rowBlocks, BLK, 0, stream>>>(seg, cv2, xd2, part4, yd2, n);
    spmm_l1<1><<<rowBlocks, BLK, 0, stream>>>(seg, cv2, xd2, part4, yd2, n);

    // 8) layer 2 + combine: out = (E + y1 + A*y1)/3
    spmm_l2<0><<<rowBlocks, BLK, 0, stream>>>(seg, cv2, yd2,
                                              (const float4*)emb, part4,
                                              (float4*)out, n);
    spmm_l2<1><<<rowBlocks, BLK, 0, stream>>>(seg, cv2, yd2,
                                              (const float4*)emb, part4,
                                              (float4*)out, n);
}

// Round 20
// 223.218 us; speedup vs baseline: 1.6270x; 1.0257x over previous
//
#include <hip/hip_runtime.h>

// DyHuCoG: out = (E + A*E + A*(A*E)) / 3
// E: [N,32] f32, A: COO (vals f32, row i32, col i32), N=100001, nE=6400000.
//
// Pipeline (atomic-free (row,colhalf)-partition, 4B edges, col-split SpMM):
//   1) tile_hist: per-8192-edge tile histogram over 782 partitions
//   2) colscan:   out-of-place column scan -> colbase + partition totals
//   3) scan_buckets: partition bases
//   4) partition_edges3: no hist pass (runoff from tileCnt row), LDS
//      reorder + coalesced run writes (TILE=8192: 10.5-edge runs)
//   5) csr_sort6: one block per partition, reads only its own range (2x),
//      256-key (rowlow) LDS-staged sort -> cv2 (4B/edge) + seg[] bases
//   6) cast emb -> bf16 pairs
//   7) layer1 in 2 col phases (3.2MB gather set, L2-resident), 8 lanes/row,
//      uint2 gathers, unroll 8: phase0 -> f32x4 partial, phase1 -> yd
//   8) layer2 same, phase1 fused with final combine (float4 I/O)

constexpr int D = 32;
constexpr int RPB_LOG = 8;               // rows per bucket = 256
constexpr int RPB = 1 << RPB_LOG;
constexpr int MAXNB = 800;               // max partitions (n <= 102400)
constexpr int TILE = 8192;               // edges per partition tile
constexpr int PT2 = 512;                 // partition threads
constexpr int CAP = 9728;                // LDS staging capacity (edges/part)
constexpr float QSCALE = 32768.0f;       // 15-bit val quantization
constexpr float QINV = 1.0f / 32768.0f;

__device__ __forceinline__ unsigned short f2bf(float f) {
    unsigned u = __float_as_uint(f);
    unsigned r = (u + 0x7FFFu + ((u >> 16) & 1u)) >> 16;   // RNE
    return (unsigned short)r;
}
__device__ __forceinline__ float lo_f(unsigned v) {       // bf16 pair low
    return __uint_as_float(v << 16);
}
__device__ __forceinline__ float hi_f(unsigned v) {       // bf16 pair high
    return __uint_as_float(v & 0xFFFF0000u);
}

__global__ void zero_f32(float* __restrict__ p, int n) {
    int i = blockIdx.x * blockDim.x + threadIdx.x;
    if (i < n) p[i] = 0.0f;
}
__global__ void cast_bf16(const float* __restrict__ in,
                          unsigned short* __restrict__ out, int n) {
    int i = blockIdx.x * blockDim.x + threadIdx.x;
    if (i < n) out[i] = f2bf(in[i]);
}

// ------- 1) per-tile partition histogram -> tileCnt[tile][NBp] -----------
__global__ __launch_bounds__(256) void tile_hist(
    const int* __restrict__ row, const int* __restrict__ col,
    int* __restrict__ tileCnt, int nE, int NBp, int half) {
    __shared__ int h[MAXNB];
    int tile = blockIdx.x;
    int base = tile * TILE;
    int n = min(TILE, nE - base);
    int t = threadIdx.x;
    for (int i = t; i < NBp; i += 256) h[i] = 0;
    __syncthreads();
    for (int i = t; i < n; i += 256) {
        int b = ((row[base + i] >> RPB_LOG) << 1) |
                ((col[base + i] >= half) ? 1 : 0);
        atomicAdd(&h[b], 1);
    }
    __syncthreads();
    for (int i = t; i < NBp; i += 256)
        tileCnt[(size_t)tile * NBp + i] = h[i];
}

// ------- 2) out-of-place column scan: tileCnt -> colbase + totals --------
__global__ __launch_bounds__(256) void colscan(
    const int* __restrict__ tileCnt, int* __restrict__ colbase,
    int* __restrict__ cnt, int nTiles, int NBp) {
    __shared__ int s2[256];
    __shared__ int carryS;
    int b = blockIdx.x, t = threadIdx.x;
    if (t == 0) carryS = 0;
    __syncthreads();
    for (int c0 = 0; c0 < nTiles; c0 += 1024) {
        int v[4], idx[4];
        int sum = 0;
#pragma unroll
        for (int k = 0; k < 4; ++k) {
            idx[k] = c0 + t * 4 + k;
            v[k] = (idx[k] < nTiles) ? tileCnt[(size_t)idx[k] * NBp + b] : 0;
            sum += v[k];
        }
        s2[t] = sum;
        __syncthreads();
        for (int o = 1; o < 256; o <<= 1) {
            int x = (t >= o) ? s2[t - o] : 0;
            __syncthreads();
            s2[t] += x;
            __syncthreads();
        }
        int run = ((t == 0) ? 0 : s2[t - 1]) + carryS;
#pragma unroll
        for (int k = 0; k < 4; ++k) {
            if (idx[k] < nTiles) colbase[(size_t)idx[k] * NBp + b] = run;
            run += v[k];
        }
        __syncthreads();
        if (t == 0) carryS += s2[255];
        __syncthreads();
    }
    if (t == 0) cnt[b] = carryS;
}

// ---------------- 3) exclusive scan of partition counts (<= 1024) --------
__global__ __launch_bounds__(1024) void scan_buckets(
    const int* __restrict__ cnt, int* __restrict__ bases, int NBp, int nE) {
    __shared__ int s[1024];
    int t = threadIdx.x;
    s[t] = (t < NBp) ? cnt[t] : 0;
    __syncthreads();
    for (int o = 1; o < 1024; o <<= 1) {
        int v = (t >= o) ? s[t - o] : 0;
        __syncthreads();
        s[t] += v;
        __syncthreads();
    }
    if (t < NBp) bases[t] = (t == 0) ? 0 : s[t - 1];
    if (t == 0) bases[NBp] = nE;
}

// ------- 4) tiled partition, NO hist pass, coalesced writes --------------
__global__ __launch_bounds__(PT2) void partition_edges3(
    const int* __restrict__ row, const int* __restrict__ col,
    const float* __restrict__ vals, const int* __restrict__ bases,
    const int* __restrict__ tileCnt, const int* __restrict__ colbase,
    uint2* __restrict__ cv, int nE, int NBp, int half) {
    __shared__ uint2 buf[TILE];            // 64 KB (also scan scratch)
    __shared__ int hist[MAXNB];            // 3.2 KB (runbase - runoff0)
    __shared__ int runoff[MAXNB];          // 3.2 KB (running local cursor)
    int* s2 = (int*)buf;                   // scratch (buf unused pre-reorder)
    int t = threadIdx.x;
    int tile = blockIdx.x;
    int base = tile * TILE;
    int n = min(TILE, nE - base);
    if (n <= 0) return;
    // local exclusive scan of tileCnt[tile][*] -> runoff (2 elems/thread)
    int b2 = t * 2;
    int a0 = (b2 + 0 < NBp) ? tileCnt[(size_t)tile * NBp + b2 + 0] : 0;
    int a1 = (b2 + 1 < NBp) ? tileCnt[(size_t)tile * NBp + b2 + 1] : 0;
    s2[t] = a0 + a1;
    __syncthreads();
    for (int o = 1; o < PT2; o <<= 1) {
        int v = (t >= o) ? s2[t - o] : 0;
        __syncthreads();
        s2[t] += v;
        __syncthreads();
    }
    {
        int excl = (t == 0) ? 0 : s2[t - 1];
        if (b2 + 0 < NBp) runoff[b2 + 0] = excl;
        if (b2 + 1 < NBp) runoff[b2 + 1] = excl + a0;
    }
    __syncthreads();
    // hist[b] := global run base - runoff0[b]
    for (int i = t; i < NBp; i += PT2)
        hist[i] = bases[i] + colbase[(size_t)tile * NBp + i] - runoff[i];
    __syncthreads();
    // reorder into LDS partition-major; partition id packed in y bits 15..24
    for (int i = t; i < n; i += PT2) {
        int r = row[base + i];
        int c = col[base + i];
        int b = ((r >> RPB_LOG) << 1) | ((c >= half) ? 1 : 0);
        int slot = atomicAdd(&runoff[b], 1);
        float v = vals[base + i];
        int q = __float2int_rn(v * QSCALE);
        q = max(0, min(32767, q));
        uint2 p;
        p.x = (unsigned)c | ((unsigned)(r & (RPB - 1)) << 17);
        p.y = (unsigned)q | ((unsigned)b << 15);
        buf[slot] = p;
    }
    __syncthreads();
    // coalesced run writes: dest = hist[b] + slot (slot == i)
    for (int i = t; i < n; i += PT2) {
        uint2 v = buf[i];
        cv[hist[v.y >> 15] + i] = v;
    }
}

// ---- 5) per-partition 256-key LDS-staged sort -> cv2 + seg --------------
__global__ __launch_bounds__(512) void csr_sort6(
    const int* __restrict__ bases, const uint2* __restrict__ cv,
    unsigned* __restrict__ cv2, int* __restrict__ seg, int nSegTot, int nE) {
    __shared__ unsigned stage[CAP];        // 38 KB
    __shared__ int hist_s[RPB];            // 1 KB
    __shared__ int cur_s[RPB];             // 1 KB
    int t = threadIdx.x;
    int p = blockIdx.x;
    int s = bases[p], e = bases[p + 1];
    if (t < RPB) hist_s[t] = 0;
    __syncthreads();
    // pass 1: rowlow histogram of own range
    for (int i = s + t; i < e; i += 512)
        atomicAdd(&hist_s[cv[i].x >> 17], 1);
    __syncthreads();
    if (t < RPB) cur_s[t] = hist_s[t];
    __syncthreads();
    for (int o = 1; o < RPB; o <<= 1) {       // inclusive scan
        int v = 0;
        if (t < RPB && t >= o) v = cur_s[t - o];
        __syncthreads();
        if (t < RPB) cur_s[t] += v;
        __syncthreads();
    }
    int excl = 0;
    if (t < RPB) excl = (t == 0) ? 0 : cur_s[t - 1];
    __syncthreads();
    if (t < RPB) {
        seg[((size_t)p << 8) | t] = s + excl;
        cur_s[t] = excl;                      // local staging cursor
    }
    if (p == 0 && t == 0) seg[nSegTot] = nE;
    __syncthreads();
    int cnt = e - s;
    bool fits = (cnt <= CAP);
    // pass 2: re-read own range, stage (or direct-scatter on overflow)
    for (int i = s + t; i < e; i += 512) {
        uint2 pr = cv[i];
        int k = (int)(pr.x >> 17);
        int slot = atomicAdd(&cur_s[k], 1);
        unsigned packed = (pr.x & 0x1FFFFu) | ((pr.y & 0x7FFFu) << 17);
        if (fits) stage[slot] = packed;
        else      cv2[s + slot] = packed;
    }
    __syncthreads();
    // pass 3: coalesced write
    if (fits) {
        for (int j = t; j < cnt; j += 512)
            cv2[s + j] = stage[j];
    }
}

// ---- 7) layer-1 SpMM, 2 phases, 8 lanes/row, uint2 gathers, unroll 8 ----
template <int PHASE>
__global__ __launch_bounds__(256) void spmm_l1(
    const int* __restrict__ seg, const unsigned* __restrict__ cv,
    const uint2* __restrict__ xd2, float4* __restrict__ part4,
    uint2* __restrict__ yd2, int nRows) {
    int g = (blockIdx.x * 256 + threadIdx.x) >> 3;
    if (g >= nRows) return;
    int lane = threadIdx.x & 7;
    int si = ((g >> 8) << 9) | (PHASE << 8) | (g & 255);
    int e = seg[si], end = seg[si + 1];
    float a0 = 0.0f, a1 = 0.0f, a2 = 0.0f, a3 = 0.0f;
    for (; e + 8 <= end; e += 8) {
        unsigned q0 = cv[e], q1 = cv[e + 1], q2 = cv[e + 2], q3 = cv[e + 3];
        unsigned q4 = cv[e + 4], q5 = cv[e + 5], q6 = cv[e + 6], q7 = cv[e + 7];
        uint2 v0 = xd2[(size_t)(q0 & 0x1FFFFu) * 8 + lane];
        uint2 v1 = xd2[(size_t)(q1 & 0x1FFFFu) * 8 + lane];
        uint2 v2 = xd2[(size_t)(q2 & 0x1FFFFu) * 8 + lane];
        uint2 v3 = xd2[(size_t)(q3 & 0x1FFFFu) * 8 + lane];
        uint2 v4 = xd2[(size_t)(q4 & 0x1FFFFu) * 8 + lane];
        uint2 v5 = xd2[(size_t)(q5 & 0x1FFFFu) * 8 + lane];
        uint2 v6 = xd2[(size_t)(q6 & 0x1FFFFu) * 8 + lane];
        uint2 v7 = xd2[(size_t)(q7 & 0x1FFFFu) * 8 + lane];
        float s0 = (float)(q0 >> 17), s1 = (float)(q1 >> 17);
        float s2 = (float)(q2 >> 17), s3 = (float)(q3 >> 17);
        float s4 = (float)(q4 >> 17), s5 = (float)(q5 >> 17);
        float s6 = (float)(q6 >> 17), s7 = (float)(q7 >> 17);
        a0 += s0 * lo_f(v0.x);  a1 += s0 * hi_f(v0.x);
        a2 += s0 * lo_f(v0.y);  a3 += s0 * hi_f(v0.y);
        a0 += s1 * lo_f(v1.x);  a1 += s1 * hi_f(v1.x);
        a2 += s1 * lo_f(v1.y);  a3 += s1 * hi_f(v1.y);
        a0 += s2 * lo_f(v2.x);  a1 += s2 * hi_f(v2.x);
        a2 += s2 * lo_f(v2.y);  a3 += s2 * hi_f(v2.y);
        a0 += s3 * lo_f(v3.x);  a1 += s3 * hi_f(v3.x);
        a2 += s3 * lo_f(v3.y);  a3 += s3 * hi_f(v3.y);
        a0 += s4 * lo_f(v4.x);  a1 += s4 * hi_f(v4.x);
        a2 += s4 * lo_f(v4.y);  a3 += s4 * hi_f(v4.y);
        a0 += s5 * lo_f(v5.x);  a1 += s5 * hi_f(v5.x);
        a2 += s5 * lo_f(v5.y);  a3 += s5 * hi_f(v5.y);
        a0 += s6 * lo_f(v6.x);  a1 += s6 * hi_f(v6.x);
        a2 += s6 * lo_f(v6.y);  a3 += s6 * hi_f(v6.y);
        a0 += s7 * lo_f(v7.x);  a1 += s7 * hi_f(v7.x);
        a2 += s7 * lo_f(v7.y);  a3 += s7 * hi_f(v7.y);
    }
    for (; e < end; ++e) {
        unsigned q = cv[e];
        uint2 v = xd2[(size_t)(q & 0x1FFFFu) * 8 + lane];
        float s = (float)(q >> 17);
        a0 += s * lo_f(v.x);  a1 += s * hi_f(v.x);
        a2 += s * lo_f(v.y);  a3 += s * hi_f(v.y);
    }
    size_t idx = (size_t)g * 8 + lane;
    if (PHASE == 0) {
        part4[idx] = make_float4(a0, a1, a2, a3);
    } else {
        float4 p = part4[idx];
        uint2 o;
        o.x = (unsigned)f2bf((p.x + a0) * QINV) |
              ((unsigned)f2bf((p.y + a1) * QINV) << 16);
        o.y = (unsigned)f2bf((p.z + a2) * QINV) |
              ((unsigned)f2bf((p.w + a3) * QINV) << 16);
        yd2[idx] = o;
    }
}

// ---- 8) layer-2 SpMM, 2 phases, phase 1 fused with combine --------------
template <int PHASE>
__global__ __launch_bounds__(256) void spmm_l2(
    const int* __restrict__ seg, const unsigned* __restrict__ cv,
    const uint2* __restrict__ yd2, const float4* __restrict__ emb4,
    float4* __restrict__ part4, float4* __restrict__ out4, int nRows) {
    int g = (blockIdx.x * 256 + threadIdx.x) >> 3;
    if (g >= nRows) return;
    int lane = threadIdx.x & 7;
    int si = ((g >> 8) << 9) | (PHASE << 8) | (g & 255);
    int e = seg[si], end = seg[si + 1];
    float a0 = 0.0f, a1 = 0.0f, a2 = 0.0f, a3 = 0.0f;
    for (; e + 8 <= end; e += 8) {
        unsigned q0 = cv[e], q1 = cv[e + 1], q2 = cv[e + 2], q3 = cv[e + 3];
        unsigned q4 = cv[e + 4], q5 = cv[e + 5], q6 = cv[e + 6], q7 = cv[e + 7];
        uint2 v0 = yd2[(size_t)(q0 & 0x1FFFFu) * 8 + lane];
        uint2 v1 = yd2[(size_t)(q1 & 0x1FFFFu) * 8 + lane];
        uint2 v2 = yd2[(size_t)(q2 & 0x1FFFFu) * 8 + lane];
        uint2 v3 = yd2[(size_t)(q3 & 0x1FFFFu) * 8 + lane];
        uint2 v4 = yd2[(size_t)(q4 & 0x1FFFFu) * 8 + lane];
        uint2 v5 = yd2[(size_t)(q5 & 0x1FFFFu) * 8 + lane];
        uint2 v6 = yd2[(size_t)(q6 & 0x1FFFFu) * 8 + lane];
        uint2 v7 = yd2[(size_t)(q7 & 0x1FFFFu) * 8 + lane];
        float s0 = (float)(q0 >> 17), s1 = (float)(q1 >> 17);
        float s2 = (float)(q2 >> 17), s3 = (float)(q3 >> 17);
        float s4 = (float)(q4 >> 17), s5 = (float)(q5 >> 17);
        float s6 = (float)(q6 >> 17), s7 = (float)(q7 >> 17);
        a0 += s0 * lo_f(v0.x);  a1 += s0 * hi_f(v0.x);
        a2 += s0 * lo_f(v0.y);  a3 += s0 * hi_f(v0.y);
        a0 += s1 * lo_f(v1.x);  a1 += s1 * hi_f(v1.x);
        a2 += s1 * lo_f(v1.y);  a3 += s1 * hi_f(v1.y);
        a0 += s2 * lo_f(v2.x);  a1 += s2 * hi_f(v2.x);
        a2 += s2 * lo_f(v2.y);  a3 += s2 * hi_f(v2.y);
        a0 += s3 * lo_f(v3.x);  a1 += s3 * hi_f(v3.x);
        a2 += s3 * lo_f(v3.y);  a3 += s3 * hi_f(v3.y);
        a0 += s4 * lo_f(v4.x);  a1 += s4 * hi_f(v4.x);
        a2 += s4 * lo_f(v4.y);  a3 += s4 * hi_f(v4.y);
        a0 += s5 * lo_f(v5.x);  a1 += s5 * hi_f(v5.x);
        a2 += s5 * lo_f(v5.y);  a3 += s5 * hi_f(v5.y);
        a0 += s6 * lo_f(v6.x);  a1 += s6 * hi_f(v6.x);
        a2 += s6 * lo_f(v6.y);  a3 += s6 * hi_f(v6.y);
        a0 += s7 * lo_f(v7.x);  a1 += s7 * hi_f(v7.x);
        a2 += s7 * lo_f(v7.y);  a3 += s7 * hi_f(v7.y);
    }
    for (; e < end; ++e) {
        unsigned q = cv[e];
        uint2 v = yd2[(size_t)(q & 0x1FFFFu) * 8 + lane];
        float s = (float)(q >> 17);
        a0 += s * lo_f(v.x);  a1 += s * hi_f(v.x);
        a2 += s * lo_f(v.y);  a3 += s * hi_f(v.y);
    }
    size_t idx = (size_t)g * 8 + lane;
    if (PHASE == 0) {
        part4[idx] = make_float4(a0, a1, a2, a3);
    } else {
        float4 eb = emb4[idx];
        uint2 yv = yd2[idx];
        float4 p = part4[idx];
        float4 r;
        r.x = (eb.x + lo_f(yv.x) + (p.x + a0) * QINV) * (1.0f / 3.0f);
        r.y = (eb.y + hi_f(yv.x) + (p.y + a1) * QINV) * (1.0f / 3.0f);
        r.z = (eb.z + lo_f(yv.y) + (p.z + a2) * QINV) * (1.0f / 3.0f);
        r.w = (eb.w + hi_f(yv.y) + (p.w + a3) * QINV) * (1.0f / 3.0f);
        out4[idx] = r;
    }
}

// =================== atomic fallback ===================
__global__ __launch_bounds__(256) void spmm_atomic(
    const int* __restrict__ row, const int* __restrict__ col,
    const float* __restrict__ vals, const float* __restrict__ x,
    float* __restrict__ y, int nEdges, float scale) {
    long long t = (long long)blockIdx.x * blockDim.x + threadIdx.x;
    int e = (int)(t >> 5);
    if (e >= nEdges) return;
    int d = (int)(t & 31);
    float g = vals[e] * scale * x[(long long)col[e] * D + d];
    atomicAdd(&y[(long long)row[e] * D + d], g);
}
__global__ void combine_third(const float* __restrict__ emb,
                              const float* __restrict__ y1,
                              float* __restrict__ out, int n) {
    int i = blockIdx.x * blockDim.x + threadIdx.x;
    if (i < n) out[i] = (emb[i] + y1[i]) * (1.0f / 3.0f);
}

extern "C" void kernel_launch(void* const* d_in, const int* in_sizes, int n_in,
                              void* d_out, int out_size, void* d_ws, size_t ws_size,
                              hipStream_t stream) {
    const float* emb  = (const float*)d_in[0];
    const float* vals = (const float*)d_in[1];
    const int*   row  = (const int*)d_in[2];
    const int*   col  = (const int*)d_in[3];
    float* out = (float*)d_out;

    const int nElem  = in_sizes[0];          // N * 32
    const int nEdges = in_sizes[1];
    const int n      = nElem / D;            // 100001
    const int NBb    = (n + RPB - 1) >> RPB_LOG;   // 256-row buckets (391)
    const int NBp    = NBb * 2;                    // partitions (782)
    const int BLK = 256;
    const int nTiles = (nEdges + TILE - 1) / TILE; // 782
    const int half   = n / 2;
    const int nSegTot = NBp * 256;                 // = NBb*512

    // workspace layout:
    //   cnt(NBp) | bases(NBp+1) | seg(nSegTot+1) | cv(8B*nE) | cv2(4B*nE)
    //   tileCnt + colbase alias cv2 (dead before csr_sort6 writes cv2)
    //   yd2 | xd2 | part4 alias cv (dead after csr_sort6)
    size_t off_cnt   = 0;                                     // NBp ints
    size_t off_bases = off_cnt + (size_t)NBp * 4;             // NBp+1 ints
    size_t off_seg   = off_bases + (size_t)(NBp + 1) * 4;     // nSegTot+1
    size_t off_cv    = (off_seg + (size_t)(nSegTot + 1) * 4 + 63) & ~(size_t)63;
    size_t off_cv2   = off_cv + (size_t)nEdges * 8;
    size_t need      = off_cv2 + (size_t)nEdges * 4;

    size_t sz_tc = (size_t)nTiles * NBp * 4;
    bool aliasFit   = ((size_t)nElem * 8 <= (size_t)nEdges * 8);
    bool tileCntFit = (2 * sz_tc <= (size_t)nEdges * 4);
    bool ok = (NBp <= MAXNB) && (n <= 102400) && (ws_size >= need) &&
              aliasFit && tileCntFit;

    if (!ok) {
        // fallback: atomic-scatter path (needs nElem floats)
        if (ws_size < (size_t)nElem * 4) return;
        float* y1 = (float*)d_ws;
        zero_f32<<<(nElem + BLK - 1) / BLK, BLK, 0, stream>>>(y1, nElem);
        long long threads = (long long)nEdges * 32;
        int blocks = (int)((threads + BLK - 1) / BLK);
        spmm_atomic<<<blocks, BLK, 0, stream>>>(row, col, vals, emb, y1, nEdges, 1.0f);
        combine_third<<<(nElem + BLK - 1) / BLK, BLK, 0, stream>>>(emb, y1, out, nElem);
        spmm_atomic<<<blocks, BLK, 0, stream>>>(row, col, vals, y1, out, nEdges, 1.0f / 3.0f);
        return;
    }

    char* ws = (char*)d_ws;
    int*            cnt     = (int*)(ws + off_cnt);
    int*            bases   = (int*)(ws + off_bases);
    int*            seg     = (int*)(ws + off_seg);
    uint2*          cv      = (uint2*)(ws + off_cv);
    unsigned*       cv2     = (unsigned*)(ws + off_cv2);
    int*            tileCnt = (int*)(ws + off_cv2);           // alias
    int*            colbase = (int*)(ws + off_cv2 + sz_tc);   // alias
    uint2*          yd2     = (uint2*)(ws + off_cv);          // alias (cv dead)
    unsigned short* embh    = (unsigned short*)(ws + off_cv + (size_t)nElem * 2);
    uint2*          xd2     = (uint2*)embh;
    float4*         part4   = (float4*)(ws + off_cv + (size_t)nElem * 4);

    // 1) per-tile partition histograms (counts, kept)
    tile_hist<<<nTiles, 256, 0, stream>>>(row, col, tileCnt, nEdges, NBp, half);

    // 2) out-of-place column scan -> colbase + partition totals
    colscan<<<NBp, 256, 0, stream>>>(tileCnt, colbase, cnt, nTiles, NBp);

    // 3) partition bases
    scan_buckets<<<1, 1024, 0, stream>>>(cnt, bases, NBp, nEdges);

    // 4) atomic-free partition (no hist pass; runoff from tileCnt row)
    partition_edges3<<<nTiles, PT2, 0, stream>>>(row, col, vals, bases,
                                                 tileCnt, colbase, cv,
                                                 nEdges, NBp, half);

    // 5) per-partition 256-key LDS-staged sort -> cv2 + seg
    csr_sort6<<<NBp, 512, 0, stream>>>(bases, cv, cv2, seg, nSegTot, nEdges);

    // 6) embh = bf16(emb)   (cv region is dead now)
    cast_bf16<<<(nElem + BLK - 1) / BLK, BLK, 0, stream>>>(emb, embh, nElem);

    // 7) layer 1: y1 = A*E, two L2-resident phases (8 lanes/row)
    int rowBlocks = (n * 8 + BLK - 1) / BLK;
    spmm_l1<0><<<rowBlocks, BLK, 0, stream>>>(seg, cv2, xd2, part4, yd2, n);
    spmm_l1<1><<<rowBlocks, BLK, 0, stream>>>(seg, cv2, xd2, part4, yd2, n);

    // 8) layer 2 + combine: out = (E + y1 + A*y1)/3
    spmm_l2<0><<<rowBlocks, BLK, 0, stream>>>(seg, cv2, yd2,
                                              (const float4*)emb, part4,
                                              (float4*)out, n);
    spmm_l2<1><<<rowBlocks, BLK, 0, stream>>>(seg, cv2, yd2,
                                              (const float4*)emb, part4,
                                              (float4*)out, n);
}